// Round 8
// baseline (2034.566 us; speedup 1.0000x reference)
//
#include <hip/hip_runtime.h>

#define NN 50000
#define NE 640000

typedef __bf16 bf16x8 __attribute__((ext_vector_type(8)));
typedef short  short8 __attribute__((ext_vector_type(8)));
typedef float  f32x16 __attribute__((ext_vector_type(16)));
typedef unsigned u32x4 __attribute__((ext_vector_type(4)));

__device__ __forceinline__ short f2bf(float v) {
  unsigned u = __builtin_bit_cast(unsigned, v);
  u = (u + 0x7FFFu + ((u >> 16) & 1u)) >> 16;   // RNE
  return (short)u;
}
__device__ __forceinline__ short f2bf_hw(float v) {
  return __builtin_bit_cast(short, (__bf16)v);
}
__device__ __forceinline__ unsigned pack2(float a, float b) {
  return (unsigned)(unsigned short)f2bf_hw(a) | ((unsigned)(unsigned short)f2bf_hw(b) << 16);
}
__device__ __forceinline__ float silu_f(float v) {
  float e = __builtin_amdgcn_exp2f(v * -1.44269504f);
  return v * __builtin_amdgcn_rcpf(1.0f + e);
}
__device__ __forceinline__ bf16x8 ld8(const short* p) {
  return *(const bf16x8*)(p);
}
__device__ __forceinline__ void atomic_add_f(float* p, float v) {
  __hip_atomic_fetch_add(p, v, __ATOMIC_RELAXED, __HIP_MEMORY_SCOPE_AGENT);
}

// ---------------- prep ----------------
// Weights: [256 n][280 k].
// w1t: k<256 = W1[k][n]; k==256 = dist row; k==257 = bias; k>=258 = 0.
// w2t/t1t/t2t: k<256 = W[k][n]; k==256 = bias[n] (folded via act 1.0 col); else 0.
// w3tab[256]: tr_w3 permuted to the D-frag register order:
//   idx = lh*128 + nt*16 + r  ->  n = nt*32 + (r&3) + 8*(r>>2) + 4*lh.
__global__ void egcl_prep(const float* __restrict__ mw1, const float* __restrict__ mb1,
                          const float* __restrict__ mw2, const float* __restrict__ mb2,
                          const float* __restrict__ tw1, const float* __restrict__ tb1,
                          const float* __restrict__ tw2, const float* __restrict__ tb2,
                          const float* __restrict__ tw3,
                          const float* __restrict__ pw1, const float* __restrict__ pw2,
                          const float* __restrict__ strf, const int* __restrict__ rowp,
                          short* __restrict__ w1t, short* __restrict__ w2t,
                          short* __restrict__ t1t, short* __restrict__ t2t,
                          short* __restrict__ p1t, short* __restrict__ p2t,
                          float* __restrict__ w3tab,
                          short* __restrict__ strb, int* __restrict__ deg)
{
  const int S0 = 71680, S2 = 98304, S3 = 32768, S4 = 256, SS = NN * 128;
  const int total = 4 * S0 + S2 + S3 + S4 + SS + NE;
  int stride = gridDim.x * blockDim.x;
  for (int i = blockIdx.x * blockDim.x + threadIdx.x; i < total; i += stride) {
    int j = i;
    if (j < S0) { int n = j / 280, k = j - n * 280;
      float v = (k < 257) ? mw1[k * 256 + n] : ((k == 257) ? mb1[n] : 0.0f);
      w1t[j] = f2bf(v); continue; }
    j -= S0;
    if (j < S0) { int n = j / 280, k = j - n * 280;
      float v = (k < 256) ? mw2[k * 256 + n] : ((k == 256) ? mb2[n] : 0.0f);
      w2t[j] = f2bf(v); continue; }
    j -= S0;
    if (j < S0) { int n = j / 280, k = j - n * 280;
      float v = (k < 256) ? tw1[k * 256 + n] : ((k == 256) ? tb1[n] : 0.0f);
      t1t[j] = f2bf(v); continue; }
    j -= S0;
    if (j < S0) { int n = j / 280, k = j - n * 280;
      float v = (k < 256) ? tw2[k * 256 + n] : ((k == 256) ? tb2[n] : 0.0f);
      t2t[j] = f2bf(v); continue; }
    j -= S0;
    if (j < S2) { int n = j / 384, k = j - n * 384; p1t[j] = f2bf(pw1[k * 256 + n]); continue; }
    j -= S2;
    if (j < S3) { int n = j >> 8, k = j & 255; p2t[j] = f2bf(pw2[k * 128 + n]); continue; }
    j -= S3;
    if (j < S4) { int lh = j >> 7, rem = j & 127, nt = rem >> 4, rr = rem & 15;
      int n = nt * 32 + (rr & 3) + 8 * (rr >> 2) + 4 * lh;
      w3tab[j] = tw3[n]; continue; }
    j -= S4;
    if (j < SS) { strb[j] = f2bf(strf[j]); continue; }
    j -= SS;
    atomicAdd(deg + rowp[j], 1);
  }
}

// ---------------- exclusive prefix scan of deg -> base (single block, R0 proven) ----
__global__ __launch_bounds__(1024)
void egcl_scan(const int* __restrict__ deg, int* __restrict__ base)
{
  __shared__ int wsum[16], wincl[16];
  __shared__ int carry_s;
  const int tid = threadIdx.x, lane = tid & 63, w = tid >> 6;
  if (tid == 0) carry_s = 0;
  __syncthreads();
  for (int start = 0; start < NN; start += 1024) {
    const int i = start + tid;
    int v = (i < NN) ? deg[i] : 0;
    int s = v;
#pragma unroll
    for (int off = 1; off < 64; off <<= 1) {
      int t = __shfl_up(s, off);
      if (lane >= off) s += t;
    }
    if (lane == 63) wsum[w] = s;
    __syncthreads();
    if (w == 0) {
      int u = (lane < 16) ? wsum[lane] : 0;
#pragma unroll
      for (int off = 1; off < 16; off <<= 1) {
        int t = __shfl_up(u, off);
        if (lane >= off) u += t;
      }
      if (lane < 16) wincl[lane] = u;
    }
    __syncthreads();
    const int waveoff = wincl[w] - wsum[w];
    const int carry = carry_s;
    if (i < NN) base[i] = carry + waveoff + s - v;
    __syncthreads();
    if (tid == 0) carry_s = carry + wincl[15];
    __syncthreads();
  }
  if (tid == 0) base[NN] = NE;
}

// ---------------- scatter edge ids into CSR buckets ----------------
__global__ void egcl_scatter(const int* __restrict__ rowp, const int* __restrict__ base,
                             int* __restrict__ cursor, int* __restrict__ eidg)
{
  int stride = gridDim.x * blockDim.x;
  for (int e = blockIdx.x * blockDim.x + threadIdx.x; e < NE; e += stride) {
    int r = rowp[e];
    int pos = base[r] + atomicAdd(cursor + r, 1);
    eidg[pos] = e;
  }
}

// ---------------- edge kernel: BARRIER-FREE, wave-private, swapped operands -------
// Each wave owns 32 edges end-to-end; ZERO __syncthreads. MFMA computes
// D^T[n][m] = W-rows x act-cols: A-frag = W[n=nt*32+l32][k chunk], B-frag lane
// holds act[m=l32][k=16ks+8lh+j] (contiguous 16B of the edge's feature row!).
// D-frag: col = l32 = edge; row n' = (r&3)+8*(r>>2)+4*lh (+32*nt).
// Layer transition (act_{L+1}-frag from D_L regs): feature n=16ks+8lh+j lives at
//   lh_src = 0 for j=0..3, 1 for j=4..7;  r = (j&3) + 8*(ks&1) + 4*lh_src; nt=ks>>1.
// -> per (nt,P): self keeps its half, ONE shfl_xor(...,32) pair exchanges the
// other: lh0 needs partner's regs {8P..8P+3}, lh1 needs partner's {8P+4..8P+7}.
// Biases fold via act k=256 = 1.0 column (K=272 all layers; L1 also dist at 256,
// bias at 257). msg written to a wave-PRIVATE LDS strip (b64-packed rows) only
// for the CSR scatter; gate & trans are wave-local register reductions.

__device__ __forceinline__ bf16x8 frag4(unsigned a, unsigned b, unsigned c, unsigned d)
{
  u32x4 t; t[0] = a; t[1] = b; t[2] = c; t[3] = d;
  return __builtin_bit_cast(bf16x8, t);
}

// b[ks] for next layer from D-regs a[8] (applies silu). ks = 2*nt + P.
__device__ __forceinline__ void form_b(const f32x16 a[8], bf16x8 b[16], int lh)
{
#pragma unroll
  for (int nt = 0; nt < 8; ++nt)
#pragma unroll
    for (int P = 0; P < 2; ++P) {
      float s0 = silu_f(a[nt][8*P+0]), s1 = silu_f(a[nt][8*P+1]);
      float s2 = silu_f(a[nt][8*P+2]), s3 = silu_f(a[nt][8*P+3]);
      float s4 = silu_f(a[nt][8*P+4]), s5 = silu_f(a[nt][8*P+5]);
      float s6 = silu_f(a[nt][8*P+6]), s7 = silu_f(a[nt][8*P+7]);
      unsigned L0 = pack2(s0, s1), L1 = pack2(s2, s3);
      unsigned H0 = pack2(s4, s5), H1 = pack2(s6, s7);
      unsigned X0 = lh ? L0 : H0, X1 = lh ? L1 : H1;   // send what partner needs
      unsigned Y0 = (unsigned)__shfl_xor((int)X0, 32);
      unsigned Y1 = (unsigned)__shfl_xor((int)X1, 32);
      unsigned W0 = lh ? Y0 : L0, W1 = lh ? Y1 : L1;
      unsigned W2 = lh ? H0 : Y0, W3 = lh ? H1 : Y1;
      b[2 * nt + P] = frag4(W0, W1, W2, W3);
    }
}

// one layer: a[nt] = sum_ks mfma(Wfrag(nt,ks), b[ks]) over 17 k-steps
__device__ __forceinline__ void gemmL(const short* __restrict__ WT,
                                      const bf16x8 b[16], bf16x8 bks16,
                                      int l32, int lh, f32x16 a[8])
{
#pragma unroll
  for (int nt = 0; nt < 8; ++nt) a[nt] = (f32x16)(0.0f);
  const short* wbase = WT + l32 * 280 + lh * 8;
#pragma unroll
  for (int ks = 0; ks < 17; ++ks) {
    const bf16x8 bb = (ks < 16) ? b[ks] : bks16;
#pragma unroll
    for (int nt = 0; nt < 8; ++nt) {
      bf16x8 w = ld8(wbase + nt * 32 * 280 + ks * 16);
      a[nt] = __builtin_amdgcn_mfma_f32_32x32x16_bf16(w, bb, a[nt], 0, 0, 0);
    }
  }
}

__global__ __launch_bounds__(256, 2)
void egcl_edge(const int* __restrict__ eidx, const float* __restrict__ coord,
               const short* __restrict__ strb, const int* __restrict__ eidg,
               const int* __restrict__ base,
               const short* __restrict__ w1t, const short* __restrict__ w2t,
               const short* __restrict__ t1t, const short* __restrict__ t2t,
               const float* __restrict__ w3tab,
               float* __restrict__ msg_sum, float* __restrict__ trans_sum)
{
  __shared__ short msg_s[4][32 * 260];   // per-wave private strips (520B rows, 8B-aligned)
  __shared__ int   rs_w[4][32];
  __shared__ int   own_w[4][32];

  const int tid  = threadIdx.x;
  const int lane = tid & 63, wave = tid >> 6;
  const int lh = lane >> 5, l32 = lane & 31;
  const int p0w = (blockIdx.x * 4 + wave) * 32;
  const int* __restrict__ rowp = eidx;
  const int* __restrict__ colp = eidx + NE;

  const int e = eidg[p0w + l32];
  const int r = rowp[e], c = colp[e];
  const float dx = coord[r * 3 + 0] - coord[c * 3 + 0];
  const float dy = coord[r * 3 + 1] - coord[c * 3 + 1];
  const float dz = coord[r * 3 + 2] - coord[c * 3 + 2];
  const float dist = dx * dx + dy * dy + dz * dz;
  if (lh == 0) {
    rs_w[wave][l32]  = r;
    own_w[wave][l32] = (base[r] >= p0w) && (base[r + 1] <= p0w + 32) ? 1 : 0;
  }

  // ---- L1 B-frags straight from global (each lane: its edge's feature chunks) ----
  bf16x8 b[16];
#pragma unroll
  for (int ks = 0; ks < 8; ++ks) b[ks]     = ld8(strb + r * 128 + ks * 16 + lh * 8);
#pragma unroll
  for (int ks = 0; ks < 8; ++ks) b[8 + ks] = ld8(strb + c * 128 + ks * 16 + lh * 8);
  bf16x8 bL1;
  {
    short8 s = (short8)(short)0;
    if (lh == 0) { s[0] = f2bf(dist); s[1] = f2bf(1.0f); }   // k=256 dist, k=257 bias
    bL1 = __builtin_bit_cast(bf16x8, s);
  }
  bf16x8 bBias;
  {
    short8 s = (short8)(short)0;
    if (lh == 0) s[0] = f2bf(1.0f);                          // k=256 bias col
    bBias = __builtin_bit_cast(bf16x8, s);
  }

  f32x16 a[8];

  gemmL(w1t, b, bL1, l32, lh, a);     // a = z1
  form_b(a, b, lh);                   // b = bf16(silu(z1)) frags
  gemmL(w2t, b, bBias, l32, lh, a);   // a = z2

  // ---- msg = silu(z2): write own row to private LDS (b64-packed) for scatter ----
  {
    short* mrow = &msg_s[wave][l32 * 260];
#pragma unroll
    for (int nt = 0; nt < 8; ++nt)
#pragma unroll
      for (int g = 0; g < 4; ++g) {     // regs r=4g..4g+3 -> n = 32nt + 8g + 4lh + 0..3
        float v0 = silu_f(a[nt][4 * g + 0]), v1 = silu_f(a[nt][4 * g + 1]);
        float v2 = silu_f(a[nt][4 * g + 2]), v3 = silu_f(a[nt][4 * g + 3]);
        uint2 uu; uu.x = pack2(v0, v1); uu.y = pack2(v2, v3);
        *(uint2*)(mrow + nt * 32 + g * 8 + lh * 4) = uu;
      }
  }
  form_b(a, b, lh);                   // b = bf16(msg) frags
  gemmL(t1t, b, bBias, l32, lh, a);   // a = z3
  form_b(a, b, lh);
  gemmL(t2t, b, bBias, l32, lh, a);   // a = z4 (bias folded)

  // ---- gate[edge] = sum_n silu(z4[n]) * w3[n]  (w3tab in register order) ----
  float g = 0.0f;
#pragma unroll
  for (int nt = 0; nt < 8; ++nt)
#pragma unroll
    for (int rg = 0; rg < 4; ++rg) {
      const float4 w = *(const float4*)(w3tab + lh * 128 + nt * 16 + rg * 4);
      g += silu_f(a[nt][4 * rg + 0]) * w.x + silu_f(a[nt][4 * rg + 1]) * w.y
         + silu_f(a[nt][4 * rg + 2]) * w.z + silu_f(a[nt][4 * rg + 3]) * w.w;
    }
  g += __shfl_xor(g, 32);             // combine feature halves

  // ---- trans: segmented scan over the wave's 32 CSR-sorted edges ----
  if (lh == 0) {
    float vx = dx * g, vy = dy * g, vz = dz * g;
#pragma unroll
    for (int off = 1; off < 32; off <<= 1) {
      int   rr = __shfl_up(r, off);
      float tx = __shfl_up(vx, off);
      float ty = __shfl_up(vy, off);
      float tz = __shfl_up(vz, off);
      if (l32 >= off && rr == r) { vx += tx; vy += ty; vz += tz; }
    }
    int rn = __shfl_down(r, 1);
    if (l32 == 31 || rn != r) {
      atomic_add_f(trans_sum + r * 3 + 0, vx);
      atomic_add_f(trans_sum + r * 3 + 1, vy);
      atomic_add_f(trans_sum + r * 3 + 2, vz);
    }
  }

  // ---- msg segment-scatter: 64 lanes x 4 cols, run over the wave's 32 edges ----
  {
    const int c0 = lane * 4;
    const short* mb = &msg_s[wave][0];
    float r0 = 0.0f, r1 = 0.0f, r2 = 0.0f, r3 = 0.0f;
    int prev = rs_w[wave][0];
    int own  = own_w[wave][0];
#pragma unroll 4
    for (int i = 0; i < 32; ++i) {
      const int ri = rs_w[wave][i];
      uint2 u = *(const uint2*)(mb + i * 260 + c0);
      float v0 = __builtin_bit_cast(float, u.x << 16);
      float v1 = __builtin_bit_cast(float, u.x & 0xFFFF0000u);
      float v2 = __builtin_bit_cast(float, u.y << 16);
      float v3 = __builtin_bit_cast(float, u.y & 0xFFFF0000u);
      if (ri != prev) {
        if (own) {
          float4 v; v.x = r0; v.y = r1; v.z = r2; v.w = r3;
          *(float4*)(msg_sum + prev * 256 + c0) = v;
        } else {
          atomic_add_f(msg_sum + prev * 256 + c0 + 0, r0);
          atomic_add_f(msg_sum + prev * 256 + c0 + 1, r1);
          atomic_add_f(msg_sum + prev * 256 + c0 + 2, r2);
          atomic_add_f(msg_sum + prev * 256 + c0 + 3, r3);
        }
        r0 = r1 = r2 = r3 = 0.0f; prev = ri; own = own_w[wave][i];
      }
      r0 += v0; r1 += v1; r2 += v2; r3 += v3;
    }
    if (own) {
      float4 v; v.x = r0; v.y = r1; v.z = r2; v.w = r3;
      *(float4*)(msg_sum + prev * 256 + c0) = v;
    } else {
      atomic_add_f(msg_sum + prev * 256 + c0 + 0, r0);
      atomic_add_f(msg_sum + prev * 256 + c0 + 1, r1);
      atomic_add_f(msg_sum + prev * 256 + c0 + 2, r2);
      atomic_add_f(msg_sum + prev * 256 + c0 + 3, r3);
    }
  }
}

// ---------------- node kernel (unchanged, proven) ----------------
__global__ __launch_bounds__(256, 3)
void egcl_node(const float* __restrict__ strf, const float* __restrict__ coord,
               const short* __restrict__ strb,
               const short* __restrict__ p1t, const short* __restrict__ p2t,
               const float* __restrict__ pb1, const float* __restrict__ pb2,
               const float* __restrict__ msg_sum, const float* __restrict__ trans_sum,
               const int* __restrict__ base, float* __restrict__ out)
{
  __shared__ short Ab[64 * 392];
  const int tid  = threadIdx.x;
  const int lane = tid & 63, wave = tid >> 6;
  const int quad = lane >> 4, l16 = lane & 15;
  const int n0 = blockIdx.x * 64;

  typedef float f32x4v __attribute__((ext_vector_type(4)));

#pragma unroll
  for (int it = 0; it < 4; ++it) {          // str cols 0..127
    int i = tid + it * 256;
    int m = i >> 4, c = i & 15;
    int n = n0 + m;
    short8 v = (short8)(short)0;
    if (n < NN) v = *(const short8*)(strb + n * 128 + c * 8);
    *(short8*)(Ab + m * 392 + c * 8) = v;
  }
#pragma unroll
  for (int it = 0; it < 8; ++it) {          // msg_sum cols 128..383
    int i = tid + it * 256;
    int m = i >> 5, c = i & 31;
    int n = n0 + m;
    short8 v = (short8)(short)0;
    if (n < NN) {
      const float* src = msg_sum + n * 256 + c * 8;
#pragma unroll
      for (int j = 0; j < 8; ++j) v[j] = f2bf_hw(src[j]);
    }
    *(short8*)(Ab + m * 392 + 128 + c * 8) = v;
  }
  __syncthreads();

  f32x4v acc[4][4];
#pragma unroll
  for (int nt = 0; nt < 4; ++nt)
#pragma unroll
    for (int mt = 0; mt < 4; ++mt) acc[nt][mt] = (f32x4v)(0.0f);
#pragma unroll
  for (int ks = 0; ks < 12; ++ks) {
    const int kb = ks * 32 + quad * 8;
    bf16x8 bv[4];
#pragma unroll
    for (int nt = 0; nt < 4; ++nt)
      bv[nt] = ld8(p1t + (wave * 64 + nt * 16 + l16) * 384 + kb);
#pragma unroll
    for (int mt = 0; mt < 4; ++mt) {
      bf16x8 av = ld8(Ab + (mt * 16 + l16) * 392 + kb);
#pragma unroll
      for (int nt = 0; nt < 4; ++nt)
        acc[nt][mt] = __builtin_amdgcn_mfma_f32_16x16x32_bf16(av, bv[nt], acc[nt][mt], 0, 0, 0);
    }
  }
  __syncthreads();
#pragma unroll
  for (int nt = 0; nt < 4; ++nt) {
    const int n = wave * 64 + nt * 16 + l16;
    const float bn = pb1[n];
#pragma unroll
    for (int mt = 0; mt < 4; ++mt)
#pragma unroll
      for (int rr = 0; rr < 4; ++rr) {
        const int m = mt * 16 + quad * 4 + rr;
        Ab[m * 392 + n] = f2bf_hw(silu_f(acc[nt][mt][rr] + bn));
      }
  }
  __syncthreads();

  f32x4v a2[2][4];
#pragma unroll
  for (int nt = 0; nt < 2; ++nt)
#pragma unroll
    for (int mt = 0; mt < 4; ++mt) a2[nt][mt] = (f32x4v)(0.0f);
#pragma unroll
  for (int ks = 0; ks < 8; ++ks) {
    const int kb = ks * 32 + quad * 8;
    bf16x8 b0 = ld8(p2t + (wave * 32 + l16) * 256 + kb);
    bf16x8 b1 = ld8(p2t + (wave * 32 + 16 + l16) * 256 + kb);
#pragma unroll
    for (int mt = 0; mt < 4; ++mt) {
      bf16x8 av = ld8(Ab + (mt * 16 + l16) * 392 + kb);
      a2[0][mt] = __builtin_amdgcn_mfma_f32_16x16x32_bf16(av, b0, a2[0][mt], 0, 0, 0);
      a2[1][mt] = __builtin_amdgcn_mfma_f32_16x16x32_bf16(av, b1, a2[1][mt], 0, 0, 0);
    }
  }
#pragma unroll
  for (int nt = 0; nt < 2; ++nt) {
    const int cc = wave * 32 + nt * 16 + l16;
    const float bc = pb2[cc];
#pragma unroll
    for (int mt = 0; mt < 4; ++mt)
#pragma unroll
      for (int rr = 0; rr < 4; ++rr) {
        const int m = mt * 16 + quad * 4 + rr;
        const int n = n0 + m;
        if (n < NN) out[n * 128 + cc] = strf[n * 128 + cc] + a2[nt][mt][rr] + bc;
      }
  }
  if (tid < 64) {
    const int n = n0 + tid;
    if (n < NN) {
      float cv = (float)(base[n + 1] - base[n]); if (cv < 1.0f) cv = 1.0f;
      float inv = __builtin_amdgcn_rcpf(cv);
      out[NN * 128 + n * 3 + 0] = coord[n * 3 + 0] + trans_sum[n * 3 + 0] * inv;
      out[NN * 128 + n * 3 + 1] = coord[n * 3 + 1] + trans_sum[n * 3 + 1] * inv;
      out[NN * 128 + n * 3 + 2] = coord[n * 3 + 2] + trans_sum[n * 3 + 2] * inv;
    }
  }
}

extern "C" void kernel_launch(void* const* d_in, const int* in_sizes, int n_in,
                              void* d_out, int out_size, void* d_ws, size_t ws_size,
                              hipStream_t stream)
{
  const int*   eidx   = (const int*)d_in[0];
  const float* strf   = (const float*)d_in[1];
  const float* coord  = (const float*)d_in[2];
  const float* msg_w1 = (const float*)d_in[3];
  const float* msg_b1 = (const float*)d_in[4];
  const float* msg_w2 = (const float*)d_in[5];
  const float* msg_b2 = (const float*)d_in[6];
  const float* tr_w1  = (const float*)d_in[7];
  const float* tr_b1  = (const float*)d_in[8];
  const float* tr_w2  = (const float*)d_in[9];
  const float* tr_b2  = (const float*)d_in[10];
  const float* tr_w3  = (const float*)d_in[11];
  const float* posi_w1 = (const float*)d_in[12];
  const float* posi_b1 = (const float*)d_in[13];
  const float* posi_w2 = (const float*)d_in[14];
  const float* posi_b2 = (const float*)d_in[15];
  float* out = (float*)d_out;

  char* ws = (char*)d_ws;
  float* msg_sum   = (float*)ws;                    // [N,256] f32     (zeroed)
  float* trans_sum = msg_sum + NN * 256;            // [N,3]           (zeroed)
  int*   deg       = (int*)(trans_sum + NN * 3);    // [N]             (zeroed)
  int*   cursor    = deg + NN;                      // [N]             (zeroed)
  int*   base      = cursor + NN;                   // [N+8]
  int*   eidg      = base + NN + 8;                 // [E]
  short* strb = (short*)(eidg + NE);                // [N,128] bf16
  short* w1t  = strb + NN * 128;                    // [256][280]
  short* w2t  = w1t + 71680;
  short* t1t  = w2t + 71680;
  short* t2t  = t1t + 71680;
  short* p1t  = t2t + 71680;                        // [256][384]
  short* p2t  = p1t + 98304;                        // [128][256]
  float* w3tab = (float*)(((uintptr_t)(p2t + 32768) + 15) & ~(uintptr_t)15);  // [256]

  const int* rowp = eidx;

  (void)hipMemsetAsync(ws, 0, (size_t)(NN * 256 + NN * 3 + NN + NN) * 4, stream);
  egcl_prep<<<2048, 256, 0, stream>>>(msg_w1, msg_b1, msg_w2, msg_b2,
                                      tr_w1, tr_b1, tr_w2, tr_b2, tr_w3,
                                      posi_w1, posi_w2,
                                      strf, rowp, w1t, w2t, t1t, t2t, p1t, p2t,
                                      w3tab, strb, deg);
  egcl_scan<<<1, 1024, 0, stream>>>(deg, base);
  egcl_scatter<<<2560, 256, 0, stream>>>(rowp, base, cursor, eidg);
  egcl_edge<<<NE / 128, 256, 0, stream>>>(eidx, coord, strb, eidg, base,
                                          w1t, w2t, t1t, t2t, w3tab,
                                          msg_sum, trans_sum);
  egcl_node<<<(NN + 63) / 64, 256, 0, stream>>>(strf, coord, strb, p1t, p2t,
                                                posi_b1, posi_b2,
                                                msg_sum, trans_sum, base, out);
}

// Round 9
// 940.503 us; speedup vs baseline: 2.1633x; 2.1633x over previous
//
#include <hip/hip_runtime.h>

#define NN 50000
#define NE 640000

typedef __bf16 bf16x8 __attribute__((ext_vector_type(8)));
typedef short  short8 __attribute__((ext_vector_type(8)));
typedef float  f32x16 __attribute__((ext_vector_type(16)));
typedef float  f32x2  __attribute__((ext_vector_type(2)));
typedef float  f32x4  __attribute__((ext_vector_type(4)));

__device__ __forceinline__ short f2bf(float v) {
  unsigned u = __builtin_bit_cast(unsigned, v);
  u = (u + 0x7FFFu + ((u >> 16) & 1u)) >> 16;   // RNE
  return (short)u;
}
__device__ __forceinline__ short f2bf_hw(float v) {
  return __builtin_bit_cast(short, (__bf16)v);
}
__device__ __forceinline__ unsigned pack2(float a, float b) {
  return (unsigned)(unsigned short)f2bf_hw(a) | ((unsigned)(unsigned short)f2bf_hw(b) << 16);
}
__device__ __forceinline__ float silu_f(float v) {
  float e = __builtin_amdgcn_exp2f(v * -1.44269504f);
  return v * __builtin_amdgcn_rcpf(1.0f + e);
}
__device__ __forceinline__ bf16x8 ld8(const short* p) {
  return *(const bf16x8*)(p);
}
__device__ __forceinline__ void atomic_add_f(float* p, float v) {
  __hip_atomic_fetch_add(p, v, __ATOMIC_RELAXED, __HIP_MEMORY_SCOPE_AGENT);
}

// ---------------- prep (R0 verbatim) ----------------
// Edge-layer weights: [256 n][280 k]; k<256 = W[k][n]; k==256 = dist-row (L1 only);
// k==257 = bias[n]; k>=258 = 0. Biases fold into GEMM via A cols 256(dist)/257(1.0).
__global__ void egcl_prep(const float* __restrict__ mw1, const float* __restrict__ mb1,
                          const float* __restrict__ mw2, const float* __restrict__ mb2,
                          const float* __restrict__ tw1, const float* __restrict__ tb1,
                          const float* __restrict__ tw2, const float* __restrict__ tb2,
                          const float* __restrict__ pw1, const float* __restrict__ pw2,
                          const float* __restrict__ strf, const int* __restrict__ rowp,
                          short* __restrict__ w1t, short* __restrict__ w2t,
                          short* __restrict__ t1t, short* __restrict__ t2t,
                          short* __restrict__ p1t, short* __restrict__ p2t,
                          short* __restrict__ strb, int* __restrict__ deg)
{
  const int S0 = 71680, S2 = 98304, S3 = 32768, SS = NN * 128;
  const int total = 4 * S0 + S2 + S3 + SS + NE;
  int stride = gridDim.x * blockDim.x;
  for (int i = blockIdx.x * blockDim.x + threadIdx.x; i < total; i += stride) {
    int j = i;
    if (j < S0) { int n = j / 280, k = j - n * 280;
      float v = (k < 257) ? mw1[k * 256 + n] : ((k == 257) ? mb1[n] : 0.0f);
      w1t[j] = f2bf(v); continue; }
    j -= S0;
    if (j < S0) { int n = j / 280, k = j - n * 280;
      float v = (k < 256) ? mw2[k * 256 + n] : ((k == 257) ? mb2[n] : 0.0f);
      w2t[j] = f2bf(v); continue; }
    j -= S0;
    if (j < S0) { int n = j / 280, k = j - n * 280;
      float v = (k < 256) ? tw1[k * 256 + n] : ((k == 257) ? tb1[n] : 0.0f);
      t1t[j] = f2bf(v); continue; }
    j -= S0;
    if (j < S0) { int n = j / 280, k = j - n * 280;
      float v = (k < 256) ? tw2[k * 256 + n] : ((k == 257) ? tb2[n] : 0.0f);
      t2t[j] = f2bf(v); continue; }
    j -= S0;
    if (j < S2) { int n = j / 384, k = j - n * 384; p1t[j] = f2bf(pw1[k * 256 + n]); continue; }
    j -= S2;
    if (j < S3) { int n = j >> 8, k = j & 255; p2t[j] = f2bf(pw2[k * 128 + n]); continue; }
    j -= S3;
    if (j < SS) { strb[j] = f2bf(strf[j]); continue; }
    j -= SS;
    atomicAdd(deg + rowp[j], 1);
  }
}

// ---------------- decoupled 3-launch scan (replaces 1-CU serial scan) -------------
// A: per-512-chunk partial sums (98 blocks). B: 1 tiny block scans the 98 partials.
// C: per-chunk exclusive write-back using the chunk offsets.
#define SCB ((NN + 511) / 512)

__global__ __launch_bounds__(512)
void egcl_scan_a(const int* __restrict__ deg, int* __restrict__ psum)
{
  __shared__ int ws[8];
  const int tid = threadIdx.x, lane = tid & 63, w = tid >> 6;
  const int i = blockIdx.x * 512 + tid;
  int s = (i < NN) ? deg[i] : 0;
#pragma unroll
  for (int off = 1; off < 64; off <<= 1) s += __shfl_xor(s, off);
  if (lane == 0) ws[w] = s;
  __syncthreads();
  if (tid == 0) {
    int t = 0;
#pragma unroll
    for (int k = 0; k < 8; ++k) t += ws[k];
    psum[blockIdx.x] = t;
  }
}

__global__ __launch_bounds__(128)
void egcl_scan_b(const int* __restrict__ psum, int* __restrict__ poff,
                 int* __restrict__ base)
{
  __shared__ int buf[128];
  const int tid = threadIdx.x;
  int v = (tid < SCB) ? psum[tid] : 0;
  buf[tid] = v;
  __syncthreads();
#pragma unroll
  for (int off = 1; off < 128; off <<= 1) {
    int t = (tid >= off) ? buf[tid - off] : 0;
    __syncthreads();
    buf[tid] += t;
    __syncthreads();
  }
  if (tid < SCB) poff[tid] = buf[tid] - v;   // exclusive
  if (tid == 0) base[NN] = NE;
}

__global__ __launch_bounds__(512)
void egcl_scan_c(const int* __restrict__ deg, const int* __restrict__ poff,
                 int* __restrict__ base)
{
  __shared__ int wsum[8], wincl[8];
  const int tid = threadIdx.x, lane = tid & 63, w = tid >> 6;
  const int i = blockIdx.x * 512 + tid;
  const int v = (i < NN) ? deg[i] : 0;
  int s = v;
#pragma unroll
  for (int off = 1; off < 64; off <<= 1) {
    int t = __shfl_up(s, off);
    if (lane >= off) s += t;
  }
  if (lane == 63) wsum[w] = s;
  __syncthreads();
  if (w == 0 && lane < 8) {
    int u = wsum[lane];
#pragma unroll
    for (int off = 1; off < 8; off <<= 1) {
      int t = __shfl_up(u, off);
      if (lane >= off) u += t;
    }
    wincl[lane] = u;
  }
  __syncthreads();
  if (i < NN) base[i] = poff[blockIdx.x] + (wincl[w] - wsum[w]) + (s - v);
}

// ---------------- scatter edge ids into CSR buckets (R0 verbatim) -----------------
__global__ void egcl_scatter(const int* __restrict__ rowp, const int* __restrict__ base,
                             int* __restrict__ cursor, int* __restrict__ eidg)
{
  int stride = gridDim.x * blockDim.x;
  for (int e = blockIdx.x * blockDim.x + threadIdx.x; e < NE; e += stride) {
    int r = rowp[e];
    int pos = base[r] + atomicAdd(cursor + r, 1);
    eidg[pos] = e;
  }
}

// ---------------- edge kernel (R0 verbatim -- 799 us proven) ----------------------
// 64-edge tiles, 256 thr, half-N passes, K=272. 4 waves, wn = wave. Wave computes
// 64(m=edges) x 64(n) in TWO 32-n passes: acc = f32x16[2] (32 AGPR) + pk staging
// (32 VGPR) -- the no-spill budget. Ab: [64][280] bf16; stride 280 shorts = 140
// words === 12 (mod 32): conflict-free b128 A-reads. Col 256 = dist, 257 = 1.0.
// A-frag: A[m=l32(+32 sm)][k=lh*8+j]; B-frag: B[k=lh*8+j][n=l32] from WT[n][k].
// D-frag: col(n)=l32; row(m)=(reg&3)+8*(reg>>2)+4*lh (+32 sm).

__device__ __forceinline__ void gemm32(const short* Ab, const short* __restrict__ WT,
                                       int wn, int nh, int lh, int l32,
                                       f32x16 acc[2])
{
  acc[0] = (f32x16)(0.0f); acc[1] = (f32x16)(0.0f);
  const short* arow = Ab + l32 * 280 + lh * 8;
  const short* brow = WT + (wn * 64 + nh * 32 + l32) * 280 + lh * 8;
#pragma unroll
  for (int ks = 0; ks < 17; ++ks) {
    const int kb = ks * 16;
    bf16x8 b  = ld8(brow + kb);
    bf16x8 a0 = ld8(arow + kb);
    bf16x8 a1 = ld8(arow + 32 * 280 + kb);
    acc[0] = __builtin_amdgcn_mfma_f32_32x32x16_bf16(a0, b, acc[0], 0, 0, 0);
    acc[1] = __builtin_amdgcn_mfma_f32_32x32x16_bf16(a1, b, acc[1], 0, 0, 0);
  }
}

__device__ __forceinline__ void comp_pack32(const f32x16 acc[2], unsigned pk[16])
{
#pragma unroll
  for (int sm = 0; sm < 2; ++sm)
#pragma unroll
    for (int j = 0; j < 8; ++j) {
      float v0 = silu_f(acc[sm][2 * j]);
      float v1 = silu_f(acc[sm][2 * j + 1]);
      pk[sm * 8 + j] = pack2(v0, v1);
    }
}

__device__ __forceinline__ void write_pk32(short* Ab, const unsigned pk0[16],
                                           const unsigned pk1[16],
                                           int wn, int lh, int l32)
{
#pragma unroll
  for (int nh = 0; nh < 2; ++nh) {
    const unsigned* pk = nh ? pk1 : pk0;
    const int n = wn * 64 + nh * 32 + l32;
#pragma unroll
    for (int sm = 0; sm < 2; ++sm) {
      short* dst = Ab + (sm * 32 + 4 * lh) * 280 + n;
#pragma unroll
      for (int j = 0; j < 8; ++j) {
        const int row = (j & 1) * 2 + 8 * (j >> 1);   // rows for regs 2j,2j+1
        const unsigned u = pk[sm * 8 + j];
        dst[row * 280]       = (short)(u & 0xFFFFu);
        dst[(row + 1) * 280] = (short)(u >> 16);
      }
    }
  }
}

__global__ __launch_bounds__(256, 4)
void egcl_edge(const int* __restrict__ eidx, const float* __restrict__ coord,
               const short* __restrict__ strb, const int* __restrict__ eidg,
               const int* __restrict__ base,
               const short* __restrict__ w1t, const short* __restrict__ w2t,
               const short* __restrict__ t1t, const short* __restrict__ t2t,
               const float* __restrict__ tr_w3,
               float* __restrict__ msg_sum, float* __restrict__ trans_sum)
{
  __shared__ short Ab[64 * 280];
  __shared__ int   rs_s[64], cs_s[64], own_s[64];
  __shared__ float cdx_s[64], cdy_s[64], cdz_s[64], gate_s[64];

  const int tid  = threadIdx.x;
  const int lane = tid & 63, wave = tid >> 6;
  const int lh = lane >> 5, l32 = lane & 31;
  const int wn = wave;
  const int p0 = blockIdx.x * 64;
  const int* __restrict__ rowp = eidx;
  const int* __restrict__ colp = eidx + NE;

  if (tid < 64) {
    int e = eidg[p0 + tid];
    int r = rowp[e], c = colp[e];
    rs_s[tid] = r; cs_s[tid] = c;
    const int wstart = p0 + (tid & ~31);           // 32-edge scatter window
    own_s[tid] = (base[r] >= wstart) && (base[r + 1] <= wstart + 32) ? 1 : 0;
    float dx = coord[r * 3 + 0] - coord[c * 3 + 0];
    float dy = coord[r * 3 + 1] - coord[c * 3 + 1];
    float dz = coord[r * 3 + 2] - coord[c * 3 + 2];
    cdx_s[tid] = dx; cdy_s[tid] = dy; cdz_s[tid] = dz;
    short8 d8 = (short8)(short)0;
    d8[0] = f2bf(dx * dx + dy * dy + dz * dz);   // col 256: dist
    d8[1] = f2bf(1.0f);                          // col 257: 1.0 (bias row)
    *(short8*)(Ab + tid * 280 + 256) = d8;
    *(short8*)(Ab + tid * 280 + 264) = (short8)(short)0;
    *(short8*)(Ab + tid * 280 + 272) = (short8)(short)0;
  }
  __syncthreads();
  // stage A cols 0..255 = [str[row] | str[col]] bf16, 16B chunks
#pragma unroll
  for (int it = 0; it < 8; ++it) {
    int i = tid + it * 256;
    int e = i >> 5, cc = i & 31;
    int node = (cc < 16) ? rs_s[e] : cs_s[e];
    short8 v = *(const short8*)(strb + node * 128 + (cc & 15) * 8);
    *(short8*)(Ab + e * 280 + cc * 8) = v;
  }
  __syncthreads();

  f32x16 acc[2];
  unsigned pk0[16], pk1[16];

  // ---- L1 ----
  gemm32(Ab, w1t, wn, 0, lh, l32, acc);
  comp_pack32(acc, pk0);
  gemm32(Ab, w1t, wn, 1, lh, l32, acc);
  comp_pack32(acc, pk1);
  __syncthreads();
  write_pk32(Ab, pk0, pk1, wn, lh, l32);
  __syncthreads();

  // ---- L2 -> msg ----
  gemm32(Ab, w2t, wn, 0, lh, l32, acc);
  comp_pack32(acc, pk0);
  gemm32(Ab, w2t, wn, 1, lh, l32, acc);
  comp_pack32(acc, pk1);
  __syncthreads();
  write_pk32(Ab, pk0, pk1, wn, lh, l32);
  __syncthreads();

  // ---- L3 gemm (reads msg) + msg segment-scatter (reads msg) ----
  gemm32(Ab, t1t, wn, 0, lh, l32, acc);
  comp_pack32(acc, pk0);
  gemm32(Ab, t1t, wn, 1, lh, l32, acc);
  comp_pack32(acc, pk1);
  {
    const int cp  = tid & 127;      // column pair: cols 2cp, 2cp+1
    const int e0w = (tid >> 7) * 32;
    float run0 = 0.0f, run1 = 0.0f;
    int prev = rs_s[e0w];
    int own  = own_s[e0w];
#pragma unroll 4
    for (int i = 0; i < 32; ++i) {
      const int idx = e0w + i;
      const int r = rs_s[idx];
      unsigned u = *(const unsigned*)(Ab + idx * 280 + cp * 2);
      float lo = __builtin_bit_cast(float, u << 16);
      float hi = __builtin_bit_cast(float, u & 0xFFFF0000u);
      if (r != prev) {
        if (own) {
          f32x2 v; v.x = run0; v.y = run1;
          *((f32x2*)msg_sum + prev * 128 + cp) = v;
        } else {
          atomic_add_f(msg_sum + prev * 256 + cp * 2 + 0, run0);
          atomic_add_f(msg_sum + prev * 256 + cp * 2 + 1, run1);
        }
        run0 = 0.0f; run1 = 0.0f; prev = r; own = own_s[idx];
      }
      run0 += lo; run1 += hi;
    }
    if (own) {
      f32x2 v; v.x = run0; v.y = run1;
      *((f32x2*)msg_sum + prev * 128 + cp) = v;
    } else {
      atomic_add_f(msg_sum + prev * 256 + cp * 2 + 0, run0);
      atomic_add_f(msg_sum + prev * 256 + cp * 2 + 1, run1);
    }
  }
  __syncthreads();
  write_pk32(Ab, pk0, pk1, wn, lh, l32);
  __syncthreads();

  // ---- L4 ----
  gemm32(Ab, t2t, wn, 0, lh, l32, acc);
  comp_pack32(acc, pk0);
  gemm32(Ab, t2t, wn, 1, lh, l32, acc);
  comp_pack32(acc, pk1);
  __syncthreads();
  write_pk32(Ab, pk0, pk1, wn, lh, l32);
  __syncthreads();

  // ---- gate = T2 @ tr_w3 (vectorized) ----
  {
    const int e = tid >> 2, p = tid & 3;
    const short* ap = Ab + e * 280 + p * 64;
    const float4* wp = (const float4*)(tr_w3 + p * 64);
    float s = 0.0f;
#pragma unroll
    for (int j = 0; j < 8; ++j) {
      bf16x8 av = ld8(ap + j * 8);
      float4 w0 = wp[2 * j], w1 = wp[2 * j + 1];
      s += (float)av[0] * w0.x + (float)av[1] * w0.y + (float)av[2] * w0.z + (float)av[3] * w0.w;
      s += (float)av[4] * w1.x + (float)av[5] * w1.y + (float)av[6] * w1.z + (float)av[7] * w1.w;
    }
    s += __shfl_xor(s, 1);
    s += __shfl_xor(s, 2);
    if (p == 0) gate_s[e] = s;
  }
  __syncthreads();
  // trans segment-reduce by row (3 threads, one per coord component)
  if (tid < 3) {
    const int c = tid;
    float run = 0.0f;
    int prev = rs_s[0];
    for (int i = 0; i < 64; ++i) {
      const int r = rs_s[i];
      if (r != prev) { atomic_add_f(trans_sum + prev * 3 + c, run); run = 0.0f; prev = r; }
      const float cd = (c == 0) ? cdx_s[i] : ((c == 1) ? cdy_s[i] : cdz_s[i]);
      run += cd * gate_s[i];
    }
    atomic_add_f(trans_sum + prev * 3 + c, run);
  }
}

// ---------------- node kernel (R0 verbatim) ----------------
__global__ __launch_bounds__(256, 3)
void egcl_node(const float* __restrict__ strf, const float* __restrict__ coord,
               const short* __restrict__ strb,
               const short* __restrict__ p1t, const short* __restrict__ p2t,
               const float* __restrict__ pb1, const float* __restrict__ pb2,
               const float* __restrict__ msg_sum, const float* __restrict__ trans_sum,
               const int* __restrict__ base, float* __restrict__ out)
{
  __shared__ short Ab[64 * 392];
  const int tid  = threadIdx.x;
  const int lane = tid & 63, wave = tid >> 6;
  const int quad = lane >> 4, l16 = lane & 15;
  const int n0 = blockIdx.x * 64;

#pragma unroll
  for (int it = 0; it < 4; ++it) {          // str cols 0..127
    int i = tid + it * 256;
    int m = i >> 4, c = i & 15;
    int n = n0 + m;
    short8 v = (short8)(short)0;
    if (n < NN) v = *(const short8*)(strb + n * 128 + c * 8);
    *(short8*)(Ab + m * 392 + c * 8) = v;
  }
#pragma unroll
  for (int it = 0; it < 8; ++it) {          // msg_sum cols 128..383
    int i = tid + it * 256;
    int m = i >> 5, c = i & 31;
    int n = n0 + m;
    short8 v = (short8)(short)0;
    if (n < NN) {
      const float* src = msg_sum + n * 256 + c * 8;
#pragma unroll
      for (int j = 0; j < 8; ++j) v[j] = f2bf_hw(src[j]);
    }
    *(short8*)(Ab + m * 392 + 128 + c * 8) = v;
  }
  __syncthreads();

  f32x4 acc[4][4];
#pragma unroll
  for (int nt = 0; nt < 4; ++nt)
#pragma unroll
    for (int mt = 0; mt < 4; ++mt) acc[nt][mt] = (f32x4)(0.0f);
#pragma unroll
  for (int ks = 0; ks < 12; ++ks) {
    const int kb = ks * 32 + quad * 8;
    bf16x8 b[4];
#pragma unroll
    for (int nt = 0; nt < 4; ++nt)
      b[nt] = ld8(p1t + (wave * 64 + nt * 16 + l16) * 384 + kb);
#pragma unroll
    for (int mt = 0; mt < 4; ++mt) {
      bf16x8 a = ld8(Ab + (mt * 16 + l16) * 392 + kb);
#pragma unroll
      for (int nt = 0; nt < 4; ++nt)
        acc[nt][mt] = __builtin_amdgcn_mfma_f32_16x16x32_bf16(a, b[nt], acc[nt][mt], 0, 0, 0);
    }
  }
  __syncthreads();
#pragma unroll
  for (int nt = 0; nt < 4; ++nt) {
    const int n = wave * 64 + nt * 16 + l16;
    const float bn = pb1[n];
#pragma unroll
    for (int mt = 0; mt < 4; ++mt)
#pragma unroll
      for (int r = 0; r < 4; ++r) {
        const int m = mt * 16 + quad * 4 + r;
        Ab[m * 392 + n] = f2bf_hw(silu_f(acc[nt][mt][r] + bn));
      }
  }
  __syncthreads();

  f32x4 a2[2][4];
#pragma unroll
  for (int nt = 0; nt < 2; ++nt)
#pragma unroll
    for (int mt = 0; mt < 4; ++mt) a2[nt][mt] = (f32x4)(0.0f);
#pragma unroll
  for (int ks = 0; ks < 8; ++ks) {
    const int kb = ks * 32 + quad * 8;
    bf16x8 b0 = ld8(p2t + (wave * 32 + l16) * 256 + kb);
    bf16x8 b1 = ld8(p2t + (wave * 32 + 16 + l16) * 256 + kb);
#pragma unroll
    for (int mt = 0; mt < 4; ++mt) {
      bf16x8 a = ld8(Ab + (mt * 16 + l16) * 392 + kb);
      a2[0][mt] = __builtin_amdgcn_mfma_f32_16x16x32_bf16(a, b0, a2[0][mt], 0, 0, 0);
      a2[1][mt] = __builtin_amdgcn_mfma_f32_16x16x32_bf16(a, b1, a2[1][mt], 0, 0, 0);
    }
  }
#pragma unroll
  for (int nt = 0; nt < 2; ++nt) {
    const int c = wave * 32 + nt * 16 + l16;
    const float bc = pb2[c];
#pragma unroll
    for (int mt = 0; mt < 4; ++mt)
#pragma unroll
      for (int r = 0; r < 4; ++r) {
        const int m = mt * 16 + quad * 4 + r;
        const int n = n0 + m;
        if (n < NN) out[n * 128 + c] = strf[n * 128 + c] + a2[nt][mt][r] + bc;
      }
  }
  if (tid < 64) {
    const int n = n0 + tid;
    if (n < NN) {
      float cv = (float)(base[n + 1] - base[n]); if (cv < 1.0f) cv = 1.0f;
      float inv = __builtin_amdgcn_rcpf(cv);
      out[NN * 128 + n * 3 + 0] = coord[n * 3 + 0] + trans_sum[n * 3 + 0] * inv;
      out[NN * 128 + n * 3 + 1] = coord[n * 3 + 1] + trans_sum[n * 3 + 1] * inv;
      out[NN * 128 + n * 3 + 2] = coord[n * 3 + 2] + trans_sum[n * 3 + 2] * inv;
    }
  }
}

extern "C" void kernel_launch(void* const* d_in, const int* in_sizes, int n_in,
                              void* d_out, int out_size, void* d_ws, size_t ws_size,
                              hipStream_t stream)
{
  const int*   eidx   = (const int*)d_in[0];
  const float* strf   = (const float*)d_in[1];
  const float* coord  = (const float*)d_in[2];
  const float* msg_w1 = (const float*)d_in[3];
  const float* msg_b1 = (const float*)d_in[4];
  const float* msg_w2 = (const float*)d_in[5];
  const float* msg_b2 = (const float*)d_in[6];
  const float* tr_w1  = (const float*)d_in[7];
  const float* tr_b1  = (const float*)d_in[8];
  const float* tr_w2  = (const float*)d_in[9];
  const float* tr_b2  = (const float*)d_in[10];
  const float* tr_w3  = (const float*)d_in[11];
  const float* posi_w1 = (const float*)d_in[12];
  const float* posi_b1 = (const float*)d_in[13];
  const float* posi_w2 = (const float*)d_in[14];
  const float* posi_b2 = (const float*)d_in[15];
  float* out = (float*)d_out;

  char* ws = (char*)d_ws;
  float* msg_sum   = (float*)ws;                    // [N,256] f32     (zeroed)
  float* trans_sum = msg_sum + NN * 256;            // [N,3]           (zeroed)
  int*   deg       = (int*)(trans_sum + NN * 3);    // [N]             (zeroed)
  int*   cursor    = deg + NN;                      // [N]             (zeroed)
  int*   base      = cursor + NN;                   // [N+8]
  int*   eidg      = base + NN + 8;                 // [E]
  short* strb = (short*)(eidg + NE);                // [N,128] bf16
  short* w1t  = strb + NN * 128;                    // [256][280]
  short* w2t  = w1t + 71680;
  short* t1t  = w2t + 71680;
  short* t2t  = t1t + 71680;
  short* p1t  = t2t + 71680;                        // [256][384]
  short* p2t  = p1t + 98304;                        // [128][256]
  int*   psum = (int*)(p2t + 32768);                // [128] scan partials
  int*   poff = psum + 128;                         // [128] scan offsets

  const int* rowp = eidx;

  (void)hipMemsetAsync(ws, 0, (size_t)(NN * 256 + NN * 3 + NN + NN) * 4, stream);
  egcl_prep<<<2048, 256, 0, stream>>>(msg_w1, msg_b1, msg_w2, msg_b2,
                                      tr_w1, tr_b1, tr_w2, tr_b2,
                                      posi_w1, posi_w2,
                                      strf, rowp, w1t, w2t, t1t, t2t, p1t, p2t, strb, deg);
  egcl_scan_a<<<SCB, 512, 0, stream>>>(deg, psum);
  egcl_scan_b<<<1, 128, 0, stream>>>(psum, poff, base);
  egcl_scan_c<<<SCB, 512, 0, stream>>>(deg, poff, base);
  egcl_scatter<<<2560, 256, 0, stream>>>(rowp, base, cursor, eidg);
  egcl_edge<<<NE / 64, 256, 0, stream>>>(eidx, coord, strb, eidg, base,
                                         w1t, w2t, t1t, t2t, tr_w3,
                                         msg_sum, trans_sum);
  egcl_node<<<(NN + 63) / 64, 256, 0, stream>>>(strf, coord, strb, p1t, p2t,
                                                posi_b1, posi_b2,
                                                msg_sum, trans_sum, base, out);
}

// Round 10
// 929.468 us; speedup vs baseline: 2.1890x; 1.0119x over previous
//
#include <hip/hip_runtime.h>

#define NN 50000
#define NE 640000

typedef __bf16 bf16x8 __attribute__((ext_vector_type(8)));
typedef short  short8 __attribute__((ext_vector_type(8)));
typedef float  f32x16 __attribute__((ext_vector_type(16)));
typedef float  f32x2  __attribute__((ext_vector_type(2)));
typedef float  f32x4  __attribute__((ext_vector_type(4)));

__device__ __forceinline__ short f2bf(float v) {
  unsigned u = __builtin_bit_cast(unsigned, v);
  u = (u + 0x7FFFu + ((u >> 16) & 1u)) >> 16;   // RNE
  return (short)u;
}
__device__ __forceinline__ short f2bf_hw(float v) {
  return __builtin_bit_cast(short, (__bf16)v);
}
__device__ __forceinline__ unsigned pack2(float a, float b) {
  return (unsigned)(unsigned short)f2bf_hw(a) | ((unsigned)(unsigned short)f2bf_hw(b) << 16);
}
__device__ __forceinline__ float silu_f(float v) {
  float e = __builtin_amdgcn_exp2f(v * -1.44269504f);
  return v * __builtin_amdgcn_rcpf(1.0f + e);
}
__device__ __forceinline__ bf16x8 ld8(const short* p) {
  return *(const bf16x8*)(p);
}
__device__ __forceinline__ void atomic_add_f(float* p, float v) {
  __hip_atomic_fetch_add(p, v, __ATOMIC_RELAXED, __HIP_MEMORY_SCOPE_AGENT);
}

// ---------------- prep (R0 verbatim) ----------------
// Edge-layer weights: [256 n][280 k]; k<256 = W[k][n]; k==256 = dist-row (L1 only);
// k==257 = bias[n]; k>=258 = 0. Biases fold into GEMM via A cols 256(dist)/257(1.0).
__global__ void egcl_prep(const float* __restrict__ mw1, const float* __restrict__ mb1,
                          const float* __restrict__ mw2, const float* __restrict__ mb2,
                          const float* __restrict__ tw1, const float* __restrict__ tb1,
                          const float* __restrict__ tw2, const float* __restrict__ tb2,
                          const float* __restrict__ pw1, const float* __restrict__ pw2,
                          const float* __restrict__ strf, const int* __restrict__ rowp,
                          short* __restrict__ w1t, short* __restrict__ w2t,
                          short* __restrict__ t1t, short* __restrict__ t2t,
                          short* __restrict__ p1t, short* __restrict__ p2t,
                          short* __restrict__ strb, int* __restrict__ deg)
{
  const int S0 = 71680, S2 = 98304, S3 = 32768, SS = NN * 128;
  const int total = 4 * S0 + S2 + S3 + SS + NE;
  int stride = gridDim.x * blockDim.x;
  for (int i = blockIdx.x * blockDim.x + threadIdx.x; i < total; i += stride) {
    int j = i;
    if (j < S0) { int n = j / 280, k = j - n * 280;
      float v = (k < 257) ? mw1[k * 256 + n] : ((k == 257) ? mb1[n] : 0.0f);
      w1t[j] = f2bf(v); continue; }
    j -= S0;
    if (j < S0) { int n = j / 280, k = j - n * 280;
      float v = (k < 256) ? mw2[k * 256 + n] : ((k == 257) ? mb2[n] : 0.0f);
      w2t[j] = f2bf(v); continue; }
    j -= S0;
    if (j < S0) { int n = j / 280, k = j - n * 280;
      float v = (k < 256) ? tw1[k * 256 + n] : ((k == 257) ? tb1[n] : 0.0f);
      t1t[j] = f2bf(v); continue; }
    j -= S0;
    if (j < S0) { int n = j / 280, k = j - n * 280;
      float v = (k < 256) ? tw2[k * 256 + n] : ((k == 257) ? tb2[n] : 0.0f);
      t2t[j] = f2bf(v); continue; }
    j -= S0;
    if (j < S2) { int n = j / 384, k = j - n * 384; p1t[j] = f2bf(pw1[k * 256 + n]); continue; }
    j -= S2;
    if (j < S3) { int n = j >> 8, k = j & 255; p2t[j] = f2bf(pw2[k * 128 + n]); continue; }
    j -= S3;
    if (j < SS) { strb[j] = f2bf(strf[j]); continue; }
    j -= SS;
    atomicAdd(deg + rowp[j], 1);
  }
}

// ---------------- decoupled 3-launch scan (R9 proven) ----------------
#define SCB ((NN + 511) / 512)

__global__ __launch_bounds__(512)
void egcl_scan_a(const int* __restrict__ deg, int* __restrict__ psum)
{
  __shared__ int ws[8];
  const int tid = threadIdx.x, lane = tid & 63, w = tid >> 6;
  const int i = blockIdx.x * 512 + tid;
  int s = (i < NN) ? deg[i] : 0;
#pragma unroll
  for (int off = 1; off < 64; off <<= 1) s += __shfl_xor(s, off);
  if (lane == 0) ws[w] = s;
  __syncthreads();
  if (tid == 0) {
    int t = 0;
#pragma unroll
    for (int k = 0; k < 8; ++k) t += ws[k];
    psum[blockIdx.x] = t;
  }
}

__global__ __launch_bounds__(128)
void egcl_scan_b(const int* __restrict__ psum, int* __restrict__ poff,
                 int* __restrict__ base)
{
  __shared__ int buf[128];
  const int tid = threadIdx.x;
  int v = (tid < SCB) ? psum[tid] : 0;
  buf[tid] = v;
  __syncthreads();
#pragma unroll
  for (int off = 1; off < 128; off <<= 1) {
    int t = (tid >= off) ? buf[tid - off] : 0;
    __syncthreads();
    buf[tid] += t;
    __syncthreads();
  }
  if (tid < SCB) poff[tid] = buf[tid] - v;   // exclusive
  if (tid == 0) base[NN] = NE;
}

__global__ __launch_bounds__(512)
void egcl_scan_c(const int* __restrict__ deg, const int* __restrict__ poff,
                 int* __restrict__ base)
{
  __shared__ int wsum[8], wincl[8];
  const int tid = threadIdx.x, lane = tid & 63, w = tid >> 6;
  const int i = blockIdx.x * 512 + tid;
  const int v = (i < NN) ? deg[i] : 0;
  int s = v;
#pragma unroll
  for (int off = 1; off < 64; off <<= 1) {
    int t = __shfl_up(s, off);
    if (lane >= off) s += t;
  }
  if (lane == 63) wsum[w] = s;
  __syncthreads();
  if (w == 0 && lane < 8) {
    int u = wsum[lane];
#pragma unroll
    for (int off = 1; off < 8; off <<= 1) {
      int t = __shfl_up(u, off);
      if (lane >= off) u += t;
    }
    wincl[lane] = u;
  }
  __syncthreads();
  if (i < NN) base[i] = poff[blockIdx.x] + (wincl[w] - wsum[w]) + (s - v);
}

// ---------------- scatter edge ids into CSR buckets (R0 verbatim) -----------------
__global__ void egcl_scatter(const int* __restrict__ rowp, const int* __restrict__ base,
                             int* __restrict__ cursor, int* __restrict__ eidg)
{
  int stride = gridDim.x * blockDim.x;
  for (int e = blockIdx.x * blockDim.x + threadIdx.x; e < NE; e += stride) {
    int r = rowp[e];
    int pos = base[r] + atomicAdd(cursor + r, 1);
    eidg[pos] = e;
  }
}

// ---------------- edge kernel (R0 verbatim -- frozen at its 795 us floor) ---------
__device__ __forceinline__ void gemm32(const short* Ab, const short* __restrict__ WT,
                                       int wn, int nh, int lh, int l32,
                                       f32x16 acc[2])
{
  acc[0] = (f32x16)(0.0f); acc[1] = (f32x16)(0.0f);
  const short* arow = Ab + l32 * 280 + lh * 8;
  const short* brow = WT + (wn * 64 + nh * 32 + l32) * 280 + lh * 8;
#pragma unroll
  for (int ks = 0; ks < 17; ++ks) {
    const int kb = ks * 16;
    bf16x8 b  = ld8(brow + kb);
    bf16x8 a0 = ld8(arow + kb);
    bf16x8 a1 = ld8(arow + 32 * 280 + kb);
    acc[0] = __builtin_amdgcn_mfma_f32_32x32x16_bf16(a0, b, acc[0], 0, 0, 0);
    acc[1] = __builtin_amdgcn_mfma_f32_32x32x16_bf16(a1, b, acc[1], 0, 0, 0);
  }
}

__device__ __forceinline__ void comp_pack32(const f32x16 acc[2], unsigned pk[16])
{
#pragma unroll
  for (int sm = 0; sm < 2; ++sm)
#pragma unroll
    for (int j = 0; j < 8; ++j) {
      float v0 = silu_f(acc[sm][2 * j]);
      float v1 = silu_f(acc[sm][2 * j + 1]);
      pk[sm * 8 + j] = pack2(v0, v1);
    }
}

__device__ __forceinline__ void write_pk32(short* Ab, const unsigned pk0[16],
                                           const unsigned pk1[16],
                                           int wn, int lh, int l32)
{
#pragma unroll
  for (int nh = 0; nh < 2; ++nh) {
    const unsigned* pk = nh ? pk1 : pk0;
    const int n = wn * 64 + nh * 32 + l32;
#pragma unroll
    for (int sm = 0; sm < 2; ++sm) {
      short* dst = Ab + (sm * 32 + 4 * lh) * 280 + n;
#pragma unroll
      for (int j = 0; j < 8; ++j) {
        const int row = (j & 1) * 2 + 8 * (j >> 1);   // rows for regs 2j,2j+1
        const unsigned u = pk[sm * 8 + j];
        dst[row * 280]       = (short)(u & 0xFFFFu);
        dst[(row + 1) * 280] = (short)(u >> 16);
      }
    }
  }
}

__global__ __launch_bounds__(256, 4)
void egcl_edge(const int* __restrict__ eidx, const float* __restrict__ coord,
               const short* __restrict__ strb, const int* __restrict__ eidg,
               const int* __restrict__ base,
               const short* __restrict__ w1t, const short* __restrict__ w2t,
               const short* __restrict__ t1t, const short* __restrict__ t2t,
               const float* __restrict__ tr_w3,
               float* __restrict__ msg_sum, float* __restrict__ trans_sum)
{
  __shared__ short Ab[64 * 280];
  __shared__ int   rs_s[64], cs_s[64], own_s[64];
  __shared__ float cdx_s[64], cdy_s[64], cdz_s[64], gate_s[64];

  const int tid  = threadIdx.x;
  const int lane = tid & 63, wave = tid >> 6;
  const int lh = lane >> 5, l32 = lane & 31;
  const int wn = wave;
  const int p0 = blockIdx.x * 64;
  const int* __restrict__ rowp = eidx;
  const int* __restrict__ colp = eidx + NE;

  if (tid < 64) {
    int e = eidg[p0 + tid];
    int r = rowp[e], c = colp[e];
    rs_s[tid] = r; cs_s[tid] = c;
    const int wstart = p0 + (tid & ~31);           // 32-edge scatter window
    own_s[tid] = (base[r] >= wstart) && (base[r + 1] <= wstart + 32) ? 1 : 0;
    float dx = coord[r * 3 + 0] - coord[c * 3 + 0];
    float dy = coord[r * 3 + 1] - coord[c * 3 + 1];
    float dz = coord[r * 3 + 2] - coord[c * 3 + 2];
    cdx_s[tid] = dx; cdy_s[tid] = dy; cdz_s[tid] = dz;
    short8 d8 = (short8)(short)0;
    d8[0] = f2bf(dx * dx + dy * dy + dz * dz);   // col 256: dist
    d8[1] = f2bf(1.0f);                          // col 257: 1.0 (bias row)
    *(short8*)(Ab + tid * 280 + 256) = d8;
    *(short8*)(Ab + tid * 280 + 264) = (short8)(short)0;
    *(short8*)(Ab + tid * 280 + 272) = (short8)(short)0;
  }
  __syncthreads();
  // stage A cols 0..255 = [str[row] | str[col]] bf16, 16B chunks
#pragma unroll
  for (int it = 0; it < 8; ++it) {
    int i = tid + it * 256;
    int e = i >> 5, cc = i & 31;
    int node = (cc < 16) ? rs_s[e] : cs_s[e];
    short8 v = *(const short8*)(strb + node * 128 + (cc & 15) * 8);
    *(short8*)(Ab + e * 280 + cc * 8) = v;
  }
  __syncthreads();

  f32x16 acc[2];
  unsigned pk0[16], pk1[16];

  // ---- L1 ----
  gemm32(Ab, w1t, wn, 0, lh, l32, acc);
  comp_pack32(acc, pk0);
  gemm32(Ab, w1t, wn, 1, lh, l32, acc);
  comp_pack32(acc, pk1);
  __syncthreads();
  write_pk32(Ab, pk0, pk1, wn, lh, l32);
  __syncthreads();

  // ---- L2 -> msg ----
  gemm32(Ab, w2t, wn, 0, lh, l32, acc);
  comp_pack32(acc, pk0);
  gemm32(Ab, w2t, wn, 1, lh, l32, acc);
  comp_pack32(acc, pk1);
  __syncthreads();
  write_pk32(Ab, pk0, pk1, wn, lh, l32);
  __syncthreads();

  // ---- L3 gemm (reads msg) + msg segment-scatter (reads msg) ----
  gemm32(Ab, t1t, wn, 0, lh, l32, acc);
  comp_pack32(acc, pk0);
  gemm32(Ab, t1t, wn, 1, lh, l32, acc);
  comp_pack32(acc, pk1);
  {
    const int cp  = tid & 127;      // column pair: cols 2cp, 2cp+1
    const int e0w = (tid >> 7) * 32;
    float run0 = 0.0f, run1 = 0.0f;
    int prev = rs_s[e0w];
    int own  = own_s[e0w];
#pragma unroll 4
    for (int i = 0; i < 32; ++i) {
      const int idx = e0w + i;
      const int r = rs_s[idx];
      unsigned u = *(const unsigned*)(Ab + idx * 280 + cp * 2);
      float lo = __builtin_bit_cast(float, u << 16);
      float hi = __builtin_bit_cast(float, u & 0xFFFF0000u);
      if (r != prev) {
        if (own) {
          f32x2 v; v.x = run0; v.y = run1;
          *((f32x2*)msg_sum + prev * 128 + cp) = v;
        } else {
          atomic_add_f(msg_sum + prev * 256 + cp * 2 + 0, run0);
          atomic_add_f(msg_sum + prev * 256 + cp * 2 + 1, run1);
        }
        run0 = 0.0f; run1 = 0.0f; prev = r; own = own_s[idx];
      }
      run0 += lo; run1 += hi;
    }
    if (own) {
      f32x2 v; v.x = run0; v.y = run1;
      *((f32x2*)msg_sum + prev * 128 + cp) = v;
    } else {
      atomic_add_f(msg_sum + prev * 256 + cp * 2 + 0, run0);
      atomic_add_f(msg_sum + prev * 256 + cp * 2 + 1, run1);
    }
  }
  __syncthreads();
  write_pk32(Ab, pk0, pk1, wn, lh, l32);
  __syncthreads();

  // ---- L4 ----
  gemm32(Ab, t2t, wn, 0, lh, l32, acc);
  comp_pack32(acc, pk0);
  gemm32(Ab, t2t, wn, 1, lh, l32, acc);
  comp_pack32(acc, pk1);
  __syncthreads();
  write_pk32(Ab, pk0, pk1, wn, lh, l32);
  __syncthreads();

  // ---- gate = T2 @ tr_w3 (vectorized) ----
  {
    const int e = tid >> 2, p = tid & 3;
    const short* ap = Ab + e * 280 + p * 64;
    const float4* wp = (const float4*)(tr_w3 + p * 64);
    float s = 0.0f;
#pragma unroll
    for (int j = 0; j < 8; ++j) {
      bf16x8 av = ld8(ap + j * 8);
      float4 w0 = wp[2 * j], w1 = wp[2 * j + 1];
      s += (float)av[0] * w0.x + (float)av[1] * w0.y + (float)av[2] * w0.z + (float)av[3] * w0.w;
      s += (float)av[4] * w1.x + (float)av[5] * w1.y + (float)av[6] * w1.z + (float)av[7] * w1.w;
    }
    s += __shfl_xor(s, 1);
    s += __shfl_xor(s, 2);
    if (p == 0) gate_s[e] = s;
  }
  __syncthreads();
  // trans segment-reduce by row (3 threads, one per coord component)
  if (tid < 3) {
    const int c = tid;
    float run = 0.0f;
    int prev = rs_s[0];
    for (int i = 0; i < 64; ++i) {
      const int r = rs_s[i];
      if (r != prev) { atomic_add_f(trans_sum + prev * 3 + c, run); run = 0.0f; prev = r; }
      const float cd = (c == 0) ? cdx_s[i] : ((c == 1) ? cdy_s[i] : cdz_s[i]);
      run += cd * gate_s[i];
    }
    atomic_add_f(trans_sum + prev * 3 + c, run);
  }
}

// ---------------- node kernel: LDS diet -> 4 blocks/CU, single-round grid ---------
// Ab shrinks to [64][264] bf16 (33.8 KB): holds msg (staged, cols 0..255 = features
// 128..383) then H1 output after GEMM1. GEMM1's str A-fragments (k 0..127) read
// directly from global strb (L2/L3-resident; same pattern as its p1t B-loads).
// 4 blocks/CU -> 1024 resident >= 782 blocks: the whole node pass runs in ONE round
// (was 2 rounds at 3/CU). Stride 264 = 132 words === 4 (mod 32): same free 2-way
// bank pattern as the old 392.
__global__ __launch_bounds__(256, 4)
void egcl_node(const float* __restrict__ strf, const float* __restrict__ coord,
               const short* __restrict__ strb,
               const short* __restrict__ p1t, const short* __restrict__ p2t,
               const float* __restrict__ pb1, const float* __restrict__ pb2,
               const float* __restrict__ msg_sum, const float* __restrict__ trans_sum,
               const int* __restrict__ base, float* __restrict__ out)
{
  __shared__ short Ab[64 * 264];
  const int tid  = threadIdx.x;
  const int lane = tid & 63, wave = tid >> 6;
  const int quad = lane >> 4, l16 = lane & 15;
  const int n0 = blockIdx.x * 64;

#pragma unroll
  for (int it = 0; it < 8; ++it) {          // msg_sum -> Ab cols 0..255 (feat 128..383)
    int i = tid + it * 256;
    int m = i >> 5, c = i & 31;
    int n = n0 + m;
    short8 v = (short8)(short)0;
    if (n < NN) {
      const float* src = msg_sum + n * 256 + c * 8;
#pragma unroll
      for (int j = 0; j < 8; ++j) v[j] = f2bf_hw(src[j]);
    }
    *(short8*)(Ab + m * 264 + c * 8) = v;
  }
  __syncthreads();

  f32x4 acc[4][4];
#pragma unroll
  for (int nt = 0; nt < 4; ++nt)
#pragma unroll
    for (int mt = 0; mt < 4; ++mt) acc[nt][mt] = (f32x4)(0.0f);
#pragma unroll
  for (int ks = 0; ks < 12; ++ks) {
    const int kb = ks * 32 + quad * 8;
    bf16x8 b[4];
#pragma unroll
    for (int nt = 0; nt < 4; ++nt)
      b[nt] = ld8(p1t + (wave * 64 + nt * 16 + l16) * 384 + kb);
#pragma unroll
    for (int mt = 0; mt < 4; ++mt) {
      bf16x8 a;
      if (ks < 4) {                          // str features 0..127: direct from global
        int nn = n0 + mt * 16 + l16; if (nn > NN - 1) nn = NN - 1;   // clamp (masked at store)
        a = ld8(strb + nn * 128 + kb);
      } else {                               // msg features 128..383: from LDS
        a = ld8(Ab + (mt * 16 + l16) * 264 + (kb - 128));
      }
#pragma unroll
      for (int nt = 0; nt < 4; ++nt)
        acc[nt][mt] = __builtin_amdgcn_mfma_f32_16x16x32_bf16(a, b[nt], acc[nt][mt], 0, 0, 0);
    }
  }
  __syncthreads();
#pragma unroll
  for (int nt = 0; nt < 4; ++nt) {
    const int n = wave * 64 + nt * 16 + l16;
    const float bn = pb1[n];
#pragma unroll
    for (int mt = 0; mt < 4; ++mt)
#pragma unroll
      for (int r = 0; r < 4; ++r) {
        const int m = mt * 16 + quad * 4 + r;
        Ab[m * 264 + n] = f2bf_hw(silu_f(acc[nt][mt][r] + bn));
      }
  }
  __syncthreads();

  f32x4 a2[2][4];
#pragma unroll
  for (int nt = 0; nt < 2; ++nt)
#pragma unroll
    for (int mt = 0; mt < 4; ++mt) a2[nt][mt] = (f32x4)(0.0f);
#pragma unroll
  for (int ks = 0; ks < 8; ++ks) {
    const int kb = ks * 32 + quad * 8;
    bf16x8 b0 = ld8(p2t + (wave * 32 + l16) * 256 + kb);
    bf16x8 b1 = ld8(p2t + (wave * 32 + 16 + l16) * 256 + kb);
#pragma unroll
    for (int mt = 0; mt < 4; ++mt) {
      bf16x8 a = ld8(Ab + (mt * 16 + l16) * 264 + kb);
      a2[0][mt] = __builtin_amdgcn_mfma_f32_16x16x32_bf16(a, b0, a2[0][mt], 0, 0, 0);
      a2[1][mt] = __builtin_amdgcn_mfma_f32_16x16x32_bf16(a, b1, a2[1][mt], 0, 0, 0);
    }
  }
#pragma unroll
  for (int nt = 0; nt < 2; ++nt) {
    const int c = wave * 32 + nt * 16 + l16;
    const float bc = pb2[c];
#pragma unroll
    for (int mt = 0; mt < 4; ++mt)
#pragma unroll
      for (int r = 0; r < 4; ++r) {
        const int m = mt * 16 + quad * 4 + r;
        const int n = n0 + m;
        if (n < NN) out[n * 128 + c] = strf[n * 128 + c] + a2[nt][mt][r] + bc;
      }
  }
  if (tid < 64) {
    const int n = n0 + tid;
    if (n < NN) {
      float cv = (float)(base[n + 1] - base[n]); if (cv < 1.0f) cv = 1.0f;
      float inv = __builtin_amdgcn_rcpf(cv);
      out[NN * 128 + n * 3 + 0] = coord[n * 3 + 0] + trans_sum[n * 3 + 0] * inv;
      out[NN * 128 + n * 3 + 1] = coord[n * 3 + 1] + trans_sum[n * 3 + 1] * inv;
      out[NN * 128 + n * 3 + 2] = coord[n * 3 + 2] + trans_sum[n * 3 + 2] * inv;
    }
  }
}

extern "C" void kernel_launch(void* const* d_in, const int* in_sizes, int n_in,
                              void* d_out, int out_size, void* d_ws, size_t ws_size,
                              hipStream_t stream)
{
  const int*   eidx   = (const int*)d_in[0];
  const float* strf   = (const float*)d_in[1];
  const float* coord  = (const float*)d_in[2];
  const float* msg_w1 = (const float*)d_in[3];
  const float* msg_b1 = (const float*)d_in[4];
  const float* msg_w2 = (const float*)d_in[5];
  const float* msg_b2 = (const float*)d_in[6];
  const float* tr_w1  = (const float*)d_in[7];
  const float* tr_b1  = (const float*)d_in[8];
  const float* tr_w2  = (const float*)d_in[9];
  const float* tr_b2  = (const float*)d_in[10];
  const float* tr_w3  = (const float*)d_in[11];
  const float* posi_w1 = (const float*)d_in[12];
  const float* posi_b1 = (const float*)d_in[13];
  const float* posi_w2 = (const float*)d_in[14];
  const float* posi_b2 = (const float*)d_in[15];
  float* out = (float*)d_out;

  char* ws = (char*)d_ws;
  float* msg_sum   = (float*)ws;                    // [N,256] f32     (zeroed)
  float* trans_sum = msg_sum + NN * 256;            // [N,3]           (zeroed)
  int*   deg       = (int*)(trans_sum + NN * 3);    // [N]             (zeroed)
  int*   cursor    = deg + NN;                      // [N]             (zeroed)
  int*   base      = cursor + NN;                   // [N+8]
  int*   eidg      = base + NN + 8;                 // [E]
  short* strb = (short*)(eidg + NE);                // [N,128] bf16
  short* w1t  = strb + NN * 128;                    // [256][280]
  short* w2t  = w1t + 71680;
  short* t1t  = w2t + 71680;
  short* t2t  = t1t + 71680;
  short* p1t  = t2t + 71680;                        // [256][384]
  short* p2t  = p1t + 98304;                        // [128][256]
  int*   psum = (int*)(p2t + 32768);                // [128] scan partials
  int*   poff = psum + 128;                         // [128] scan offsets

  const int* rowp = eidx;

  (void)hipMemsetAsync(ws, 0, (size_t)(NN * 256 + NN * 3 + NN + NN) * 4, stream);
  egcl_prep<<<2048, 256, 0, stream>>>(msg_w1, msg_b1, msg_w2, msg_b2,
                                      tr_w1, tr_b1, tr_w2, tr_b2,
                                      posi_w1, posi_w2,
                                      strf, rowp, w1t, w2t, t1t, t2t, p1t, p2t, strb, deg);
  egcl_scan_a<<<SCB, 512, 0, stream>>>(deg, psum);
  egcl_scan_b<<<1, 128, 0, stream>>>(psum, poff, base);
  egcl_scan_c<<<SCB, 512, 0, stream>>>(deg, poff, base);
  egcl_scatter<<<2560, 256, 0, stream>>>(rowp, base, cursor, eidg);
  egcl_edge<<<NE / 64, 256, 0, stream>>>(eidx, coord, strb, eidg, base,
                                         w1t, w2t, t1t, t2t, tr_w3,
                                         msg_sum, trans_sum);
  egcl_node<<<(NN + 63) / 64, 256, 0, stream>>>(strf, coord, strb, p1t, p2t,
                                                posi_b1, posi_b2,
                                                msg_sum, trans_sum, base, out);
}

// Round 11
// 926.996 us; speedup vs baseline: 2.1948x; 1.0027x over previous
//
#include <hip/hip_runtime.h>

#define NN 50000
#define NE 640000

typedef __bf16 bf16x8 __attribute__((ext_vector_type(8)));
typedef short  short8 __attribute__((ext_vector_type(8)));
typedef float  f32x16 __attribute__((ext_vector_type(16)));
typedef float  f32x2  __attribute__((ext_vector_type(2)));
typedef float  f32x4  __attribute__((ext_vector_type(4)));

__device__ __forceinline__ short f2bf(float v) {
  unsigned u = __builtin_bit_cast(unsigned, v);
  u = (u + 0x7FFFu + ((u >> 16) & 1u)) >> 16;   // RNE
  return (short)u;
}
__device__ __forceinline__ short f2bf_hw(float v) {
  return __builtin_bit_cast(short, (__bf16)v);
}
__device__ __forceinline__ unsigned pack2(float a, float b) {
  return (unsigned)(unsigned short)f2bf_hw(a) | ((unsigned)(unsigned short)f2bf_hw(b) << 16);
}
__device__ __forceinline__ float silu_f(float v) {
  float e = __builtin_amdgcn_exp2f(v * -1.44269504f);
  return v * __builtin_amdgcn_rcpf(1.0f + e);
}
__device__ __forceinline__ bf16x8 ld8(const short* p) {
  return *(const bf16x8*)(p);
}
__device__ __forceinline__ void atomic_add_f(float* p, float v) {
  __hip_atomic_fetch_add(p, v, __ATOMIC_RELAXED, __HIP_MEMORY_SCOPE_AGENT);
}

// ---------------- prep (R0 + fused msg_sum/trans_sum zeroing) ----------------
// Edge-layer weights: [256 n][280 k]; k<256 = W[k][n]; k==256 = dist-row (L1 only);
// k==257 = bias[n]; k>=258 = 0. Biases fold into GEMM via A cols 256(dist)/257(1.0).
// zf4: msg_sum|trans_sum region as float4 zero-stores (NN*259 floats, /4 exact).
#define ZS ((NN * 259) / 4)

__global__ void egcl_prep(const float* __restrict__ mw1, const float* __restrict__ mb1,
                          const float* __restrict__ mw2, const float* __restrict__ mb2,
                          const float* __restrict__ tw1, const float* __restrict__ tb1,
                          const float* __restrict__ tw2, const float* __restrict__ tb2,
                          const float* __restrict__ pw1, const float* __restrict__ pw2,
                          const float* __restrict__ strf, const int* __restrict__ rowp,
                          short* __restrict__ w1t, short* __restrict__ w2t,
                          short* __restrict__ t1t, short* __restrict__ t2t,
                          short* __restrict__ p1t, short* __restrict__ p2t,
                          short* __restrict__ strb, int* __restrict__ deg,
                          float* __restrict__ zf4)
{
  const int S0 = 71680, S2 = 98304, S3 = 32768, SS = NN * 128;
  const int total = ZS + 4 * S0 + S2 + S3 + SS + NE;
  int stride = gridDim.x * blockDim.x;
  for (int i = blockIdx.x * blockDim.x + threadIdx.x; i < total; i += stride) {
    int j = i;
    if (j < ZS) {
      float4 z; z.x = 0.0f; z.y = 0.0f; z.z = 0.0f; z.w = 0.0f;
      *(float4*)(zf4 + (size_t)j * 4) = z; continue; }
    j -= ZS;
    if (j < S0) { int n = j / 280, k = j - n * 280;
      float v = (k < 257) ? mw1[k * 256 + n] : ((k == 257) ? mb1[n] : 0.0f);
      w1t[j] = f2bf(v); continue; }
    j -= S0;
    if (j < S0) { int n = j / 280, k = j - n * 280;
      float v = (k < 256) ? mw2[k * 256 + n] : ((k == 257) ? mb2[n] : 0.0f);
      w2t[j] = f2bf(v); continue; }
    j -= S0;
    if (j < S0) { int n = j / 280, k = j - n * 280;
      float v = (k < 256) ? tw1[k * 256 + n] : ((k == 257) ? tb1[n] : 0.0f);
      t1t[j] = f2bf(v); continue; }
    j -= S0;
    if (j < S0) { int n = j / 280, k = j - n * 280;
      float v = (k < 256) ? tw2[k * 256 + n] : ((k == 257) ? tb2[n] : 0.0f);
      t2t[j] = f2bf(v); continue; }
    j -= S0;
    if (j < S2) { int n = j / 384, k = j - n * 384; p1t[j] = f2bf(pw1[k * 256 + n]); continue; }
    j -= S2;
    if (j < S3) { int n = j >> 8, k = j & 255; p2t[j] = f2bf(pw2[k * 128 + n]); continue; }
    j -= S3;
    if (j < SS) { strb[j] = f2bf(strf[j]); continue; }
    j -= SS;
    atomicAdd(deg + rowp[j], 1);
  }
}

// ---------------- decoupled 3-launch scan (R9 proven) ----------------
#define SCB ((NN + 511) / 512)

__global__ __launch_bounds__(512)
void egcl_scan_a(const int* __restrict__ deg, int* __restrict__ psum)
{
  __shared__ int ws[8];
  const int tid = threadIdx.x, lane = tid & 63, w = tid >> 6;
  const int i = blockIdx.x * 512 + tid;
  int s = (i < NN) ? deg[i] : 0;
#pragma unroll
  for (int off = 1; off < 64; off <<= 1) s += __shfl_xor(s, off);
  if (lane == 0) ws[w] = s;
  __syncthreads();
  if (tid == 0) {
    int t = 0;
#pragma unroll
    for (int k = 0; k < 8; ++k) t += ws[k];
    psum[blockIdx.x] = t;
  }
}

__global__ __launch_bounds__(128)
void egcl_scan_b(const int* __restrict__ psum, int* __restrict__ poff,
                 int* __restrict__ base)
{
  __shared__ int buf[128];
  const int tid = threadIdx.x;
  int v = (tid < SCB) ? psum[tid] : 0;
  buf[tid] = v;
  __syncthreads();
#pragma unroll
  for (int off = 1; off < 128; off <<= 1) {
    int t = (tid >= off) ? buf[tid - off] : 0;
    __syncthreads();
    buf[tid] += t;
    __syncthreads();
  }
  if (tid < SCB) poff[tid] = buf[tid] - v;   // exclusive
  if (tid == 0) base[NN] = NE;
}

__global__ __launch_bounds__(512)
void egcl_scan_c(const int* __restrict__ deg, const int* __restrict__ poff,
                 int* __restrict__ base)
{
  __shared__ int wsum[8], wincl[8];
  const int tid = threadIdx.x, lane = tid & 63, w = tid >> 6;
  const int i = blockIdx.x * 512 + tid;
  const int v = (i < NN) ? deg[i] : 0;
  int s = v;
#pragma unroll
  for (int off = 1; off < 64; off <<= 1) {
    int t = __shfl_up(s, off);
    if (lane >= off) s += t;
  }
  if (lane == 63) wsum[w] = s;
  __syncthreads();
  if (w == 0 && lane < 8) {
    int u = wsum[lane];
#pragma unroll
    for (int off = 1; off < 8; off <<= 1) {
      int t = __shfl_up(u, off);
      if (lane >= off) u += t;
    }
    wincl[lane] = u;
  }
  __syncthreads();
  if (i < NN) base[i] = poff[blockIdx.x] + (wincl[w] - wsum[w]) + (s - v);
}

// ---------------- scatter edge ids into CSR buckets (exact grid) ------------------
__global__ __launch_bounds__(512)
void egcl_scatter(const int* __restrict__ rowp, const int* __restrict__ base,
                  int* __restrict__ cursor, int* __restrict__ eidg)
{
  const int e = blockIdx.x * 512 + threadIdx.x;
  if (e < NE) {
    int r = rowp[e];
    int pos = base[r] + atomicAdd(cursor + r, 1);
    eidg[pos] = e;
  }
}

// ---------------- edge kernel (R0 verbatim -- frozen at its 794 us floor) ---------
__device__ __forceinline__ void gemm32(const short* Ab, const short* __restrict__ WT,
                                       int wn, int nh, int lh, int l32,
                                       f32x16 acc[2])
{
  acc[0] = (f32x16)(0.0f); acc[1] = (f32x16)(0.0f);
  const short* arow = Ab + l32 * 280 + lh * 8;
  const short* brow = WT + (wn * 64 + nh * 32 + l32) * 280 + lh * 8;
#pragma unroll
  for (int ks = 0; ks < 17; ++ks) {
    const int kb = ks * 16;
    bf16x8 b  = ld8(brow + kb);
    bf16x8 a0 = ld8(arow + kb);
    bf16x8 a1 = ld8(arow + 32 * 280 + kb);
    acc[0] = __builtin_amdgcn_mfma_f32_32x32x16_bf16(a0, b, acc[0], 0, 0, 0);
    acc[1] = __builtin_amdgcn_mfma_f32_32x32x16_bf16(a1, b, acc[1], 0, 0, 0);
  }
}

__device__ __forceinline__ void comp_pack32(const f32x16 acc[2], unsigned pk[16])
{
#pragma unroll
  for (int sm = 0; sm < 2; ++sm)
#pragma unroll
    for (int j = 0; j < 8; ++j) {
      float v0 = silu_f(acc[sm][2 * j]);
      float v1 = silu_f(acc[sm][2 * j + 1]);
      pk[sm * 8 + j] = pack2(v0, v1);
    }
}

__device__ __forceinline__ void write_pk32(short* Ab, const unsigned pk0[16],
                                           const unsigned pk1[16],
                                           int wn, int lh, int l32)
{
#pragma unroll
  for (int nh = 0; nh < 2; ++nh) {
    const unsigned* pk = nh ? pk1 : pk0;
    const int n = wn * 64 + nh * 32 + l32;
#pragma unroll
    for (int sm = 0; sm < 2; ++sm) {
      short* dst = Ab + (sm * 32 + 4 * lh) * 280 + n;
#pragma unroll
      for (int j = 0; j < 8; ++j) {
        const int row = (j & 1) * 2 + 8 * (j >> 1);   // rows for regs 2j,2j+1
        const unsigned u = pk[sm * 8 + j];
        dst[row * 280]       = (short)(u & 0xFFFFu);
        dst[(row + 1) * 280] = (short)(u >> 16);
      }
    }
  }
}

__global__ __launch_bounds__(256, 4)
void egcl_edge(const int* __restrict__ eidx, const float* __restrict__ coord,
               const short* __restrict__ strb, const int* __restrict__ eidg,
               const int* __restrict__ base,
               const short* __restrict__ w1t, const short* __restrict__ w2t,
               const short* __restrict__ t1t, const short* __restrict__ t2t,
               const float* __restrict__ tr_w3,
               float* __restrict__ msg_sum, float* __restrict__ trans_sum)
{
  __shared__ short Ab[64 * 280];
  __shared__ int   rs_s[64], cs_s[64], own_s[64];
  __shared__ float cdx_s[64], cdy_s[64], cdz_s[64], gate_s[64];

  const int tid  = threadIdx.x;
  const int lane = tid & 63, wave = tid >> 6;
  const int lh = lane >> 5, l32 = lane & 31;
  const int wn = wave;
  const int p0 = blockIdx.x * 64;
  const int* __restrict__ rowp = eidx;
  const int* __restrict__ colp = eidx + NE;

  if (tid < 64) {
    int e = eidg[p0 + tid];
    int r = rowp[e], c = colp[e];
    rs_s[tid] = r; cs_s[tid] = c;
    const int wstart = p0 + (tid & ~31);           // 32-edge scatter window
    own_s[tid] = (base[r] >= wstart) && (base[r + 1] <= wstart + 32) ? 1 : 0;
    float dx = coord[r * 3 + 0] - coord[c * 3 + 0];
    float dy = coord[r * 3 + 1] - coord[c * 3 + 1];
    float dz = coord[r * 3 + 2] - coord[c * 3 + 2];
    cdx_s[tid] = dx; cdy_s[tid] = dy; cdz_s[tid] = dz;
    short8 d8 = (short8)(short)0;
    d8[0] = f2bf(dx * dx + dy * dy + dz * dz);   // col 256: dist
    d8[1] = f2bf(1.0f);                          // col 257: 1.0 (bias row)
    *(short8*)(Ab + tid * 280 + 256) = d8;
    *(short8*)(Ab + tid * 280 + 264) = (short8)(short)0;
    *(short8*)(Ab + tid * 280 + 272) = (short8)(short)0;
  }
  __syncthreads();
  // stage A cols 0..255 = [str[row] | str[col]] bf16, 16B chunks
#pragma unroll
  for (int it = 0; it < 8; ++it) {
    int i = tid + it * 256;
    int e = i >> 5, cc = i & 31;
    int node = (cc < 16) ? rs_s[e] : cs_s[e];
    short8 v = *(const short8*)(strb + node * 128 + (cc & 15) * 8);
    *(short8*)(Ab + e * 280 + cc * 8) = v;
  }
  __syncthreads();

  f32x16 acc[2];
  unsigned pk0[16], pk1[16];

  // ---- L1 ----
  gemm32(Ab, w1t, wn, 0, lh, l32, acc);
  comp_pack32(acc, pk0);
  gemm32(Ab, w1t, wn, 1, lh, l32, acc);
  comp_pack32(acc, pk1);
  __syncthreads();
  write_pk32(Ab, pk0, pk1, wn, lh, l32);
  __syncthreads();

  // ---- L2 -> msg ----
  gemm32(Ab, w2t, wn, 0, lh, l32, acc);
  comp_pack32(acc, pk0);
  gemm32(Ab, w2t, wn, 1, lh, l32, acc);
  comp_pack32(acc, pk1);
  __syncthreads();
  write_pk32(Ab, pk0, pk1, wn, lh, l32);
  __syncthreads();

  // ---- L3 gemm (reads msg) + msg segment-scatter (reads msg) ----
  gemm32(Ab, t1t, wn, 0, lh, l32, acc);
  comp_pack32(acc, pk0);
  gemm32(Ab, t1t, wn, 1, lh, l32, acc);
  comp_pack32(acc, pk1);
  {
    const int cp  = tid & 127;      // column pair: cols 2cp, 2cp+1
    const int e0w = (tid >> 7) * 32;
    float run0 = 0.0f, run1 = 0.0f;
    int prev = rs_s[e0w];
    int own  = own_s[e0w];
#pragma unroll 4
    for (int i = 0; i < 32; ++i) {
      const int idx = e0w + i;
      const int r = rs_s[idx];
      unsigned u = *(const unsigned*)(Ab + idx * 280 + cp * 2);
      float lo = __builtin_bit_cast(float, u << 16);
      float hi = __builtin_bit_cast(float, u & 0xFFFF0000u);
      if (r != prev) {
        if (own) {
          f32x2 v; v.x = run0; v.y = run1;
          *((f32x2*)msg_sum + prev * 128 + cp) = v;
        } else {
          atomic_add_f(msg_sum + prev * 256 + cp * 2 + 0, run0);
          atomic_add_f(msg_sum + prev * 256 + cp * 2 + 1, run1);
        }
        run0 = 0.0f; run1 = 0.0f; prev = r; own = own_s[idx];
      }
      run0 += lo; run1 += hi;
    }
    if (own) {
      f32x2 v; v.x = run0; v.y = run1;
      *((f32x2*)msg_sum + prev * 128 + cp) = v;
    } else {
      atomic_add_f(msg_sum + prev * 256 + cp * 2 + 0, run0);
      atomic_add_f(msg_sum + prev * 256 + cp * 2 + 1, run1);
    }
  }
  __syncthreads();
  write_pk32(Ab, pk0, pk1, wn, lh, l32);
  __syncthreads();

  // ---- L4 ----
  gemm32(Ab, t2t, wn, 0, lh, l32, acc);
  comp_pack32(acc, pk0);
  gemm32(Ab, t2t, wn, 1, lh, l32, acc);
  comp_pack32(acc, pk1);
  __syncthreads();
  write_pk32(Ab, pk0, pk1, wn, lh, l32);
  __syncthreads();

  // ---- gate = T2 @ tr_w3 (vectorized) ----
  {
    const int e = tid >> 2, p = tid & 3;
    const short* ap = Ab + e * 280 + p * 64;
    const float4* wp = (const float4*)(tr_w3 + p * 64);
    float s = 0.0f;
#pragma unroll
    for (int j = 0; j < 8; ++j) {
      bf16x8 av = ld8(ap + j * 8);
      float4 w0 = wp[2 * j], w1 = wp[2 * j + 1];
      s += (float)av[0] * w0.x + (float)av[1] * w0.y + (float)av[2] * w0.z + (float)av[3] * w0.w;
      s += (float)av[4] * w1.x + (float)av[5] * w1.y + (float)av[6] * w1.z + (float)av[7] * w1.w;
    }
    s += __shfl_xor(s, 1);
    s += __shfl_xor(s, 2);
    if (p == 0) gate_s[e] = s;
  }
  __syncthreads();
  // trans segment-reduce by row (3 threads, one per coord component)
  if (tid < 3) {
    const int c = tid;
    float run = 0.0f;
    int prev = rs_s[0];
    for (int i = 0; i < 64; ++i) {
      const int r = rs_s[i];
      if (r != prev) { atomic_add_f(trans_sum + prev * 3 + c, run); run = 0.0f; prev = r; }
      const float cd = (c == 0) ? cdx_s[i] : ((c == 1) ? cdy_s[i] : cdz_s[i]);
      run += cd * gate_s[i];
    }
    atomic_add_f(trans_sum + prev * 3 + c, run);
  }
}

// ---------------- node kernel (R10 + vectorized msg staging) ----------------------
__global__ __launch_bounds__(256, 4)
void egcl_node(const float* __restrict__ strf, const float* __restrict__ coord,
               const short* __restrict__ strb,
               const short* __restrict__ p1t, const short* __restrict__ p2t,
               const float* __restrict__ pb1, const float* __restrict__ pb2,
               const float* __restrict__ msg_sum, const float* __restrict__ trans_sum,
               const int* __restrict__ base, float* __restrict__ out)
{
  __shared__ short Ab[64 * 264];
  const int tid  = threadIdx.x;
  const int lane = tid & 63, wave = tid >> 6;
  const int quad = lane >> 4, l16 = lane & 15;
  const int n0 = blockIdx.x * 64;

#pragma unroll
  for (int it = 0; it < 8; ++it) {          // msg_sum -> Ab cols 0..255 (feat 128..383)
    int i = tid + it * 256;
    int m = i >> 5, c = i & 31;
    int n = n0 + m;
    short8 v = (short8)(short)0;
    if (n < NN) {
      const float4* src = (const float4*)(msg_sum + n * 256 + c * 8);
      float4 f0 = src[0], f1 = src[1];
      v[0] = f2bf_hw(f0.x); v[1] = f2bf_hw(f0.y); v[2] = f2bf_hw(f0.z); v[3] = f2bf_hw(f0.w);
      v[4] = f2bf_hw(f1.x); v[5] = f2bf_hw(f1.y); v[6] = f2bf_hw(f1.z); v[7] = f2bf_hw(f1.w);
    }
    *(short8*)(Ab + m * 264 + c * 8) = v;
  }
  __syncthreads();

  f32x4 acc[4][4];
#pragma unroll
  for (int nt = 0; nt < 4; ++nt)
#pragma unroll
    for (int mt = 0; mt < 4; ++mt) acc[nt][mt] = (f32x4)(0.0f);
#pragma unroll
  for (int ks = 0; ks < 12; ++ks) {
    const int kb = ks * 32 + quad * 8;
    bf16x8 b[4];
#pragma unroll
    for (int nt = 0; nt < 4; ++nt)
      b[nt] = ld8(p1t + (wave * 64 + nt * 16 + l16) * 384 + kb);
#pragma unroll
    for (int mt = 0; mt < 4; ++mt) {
      bf16x8 a;
      if (ks < 4) {                          // str features 0..127: direct from global
        int nn = n0 + mt * 16 + l16; if (nn > NN - 1) nn = NN - 1;   // clamp (masked at store)
        a = ld8(strb + nn * 128 + kb);
      } else {                               // msg features 128..383: from LDS
        a = ld8(Ab + (mt * 16 + l16) * 264 + (kb - 128));
      }
#pragma unroll
      for (int nt = 0; nt < 4; ++nt)
        acc[nt][mt] = __builtin_amdgcn_mfma_f32_16x16x32_bf16(a, b[nt], acc[nt][mt], 0, 0, 0);
    }
  }
  __syncthreads();
#pragma unroll
  for (int nt = 0; nt < 4; ++nt) {
    const int n = wave * 64 + nt * 16 + l16;
    const float bn = pb1[n];
#pragma unroll
    for (int mt = 0; mt < 4; ++mt)
#pragma unroll
      for (int r = 0; r < 4; ++r) {
        const int m = mt * 16 + quad * 4 + r;
        Ab[m * 264 + n] = f2bf_hw(silu_f(acc[nt][mt][r] + bn));
      }
  }
  __syncthreads();

  f32x4 a2[2][4];
#pragma unroll
  for (int nt = 0; nt < 2; ++nt)
#pragma unroll
    for (int mt = 0; mt < 4; ++mt) a2[nt][mt] = (f32x4)(0.0f);
#pragma unroll
  for (int ks = 0; ks < 8; ++ks) {
    const int kb = ks * 32 + quad * 8;
    bf16x8 b0 = ld8(p2t + (wave * 32 + l16) * 256 + kb);
    bf16x8 b1 = ld8(p2t + (wave * 32 + 16 + l16) * 256 + kb);
#pragma unroll
    for (int mt = 0; mt < 4; ++mt) {
      bf16x8 a = ld8(Ab + (mt * 16 + l16) * 264 + kb);
      a2[0][mt] = __builtin_amdgcn_mfma_f32_16x16x32_bf16(a, b0, a2[0][mt], 0, 0, 0);
      a2[1][mt] = __builtin_amdgcn_mfma_f32_16x16x32_bf16(a, b1, a2[1][mt], 0, 0, 0);
    }
  }
#pragma unroll
  for (int nt = 0; nt < 2; ++nt) {
    const int c = wave * 32 + nt * 16 + l16;
    const float bc = pb2[c];
#pragma unroll
    for (int mt = 0; mt < 4; ++mt)
#pragma unroll
      for (int r = 0; r < 4; ++r) {
        const int m = mt * 16 + quad * 4 + r;
        const int n = n0 + m;
        if (n < NN) out[n * 128 + c] = strf[n * 128 + c] + a2[nt][mt][r] + bc;
      }
  }
  if (tid < 64) {
    const int n = n0 + tid;
    if (n < NN) {
      float cv = (float)(base[n + 1] - base[n]); if (cv < 1.0f) cv = 1.0f;
      float inv = __builtin_amdgcn_rcpf(cv);
      out[NN * 128 + n * 3 + 0] = coord[n * 3 + 0] + trans_sum[n * 3 + 0] * inv;
      out[NN * 128 + n * 3 + 1] = coord[n * 3 + 1] + trans_sum[n * 3 + 1] * inv;
      out[NN * 128 + n * 3 + 2] = coord[n * 3 + 2] + trans_sum[n * 3 + 2] * inv;
    }
  }
}

extern "C" void kernel_launch(void* const* d_in, const int* in_sizes, int n_in,
                              void* d_out, int out_size, void* d_ws, size_t ws_size,
                              hipStream_t stream)
{
  const int*   eidx   = (const int*)d_in[0];
  const float* strf   = (const float*)d_in[1];
  const float* coord  = (const float*)d_in[2];
  const float* msg_w1 = (const float*)d_in[3];
  const float* msg_b1 = (const float*)d_in[4];
  const float* msg_w2 = (const float*)d_in[5];
  const float* msg_b2 = (const float*)d_in[6];
  const float* tr_w1  = (const float*)d_in[7];
  const float* tr_b1  = (const float*)d_in[8];
  const float* tr_w2  = (const float*)d_in[9];
  const float* tr_b2  = (const float*)d_in[10];
  const float* tr_w3  = (const float*)d_in[11];
  const float* posi_w1 = (const float*)d_in[12];
  const float* posi_b1 = (const float*)d_in[13];
  const float* posi_w2 = (const float*)d_in[14];
  const float* posi_b2 = (const float*)d_in[15];
  float* out = (float*)d_out;

  char* ws = (char*)d_ws;
  float* msg_sum   = (float*)ws;                    // [N,256] f32  (zeroed in prep)
  float* trans_sum = msg_sum + NN * 256;            // [N,3]        (zeroed in prep)
  int*   deg       = (int*)(trans_sum + NN * 3);    // [N]          (zeroed by memset)
  int*   cursor    = deg + NN;                      // [N]          (zeroed by memset)
  int*   base      = cursor + NN;                   // [N+8]
  int*   eidg      = base + NN + 8;                 // [E]
  short* strb = (short*)(eidg + NE);                // [N,128] bf16
  short* w1t  = strb + NN * 128;                    // [256][280]
  short* w2t  = w1t + 71680;
  short* t1t  = w2t + 71680;
  short* t2t  = t1t + 71680;
  short* p1t  = t2t + 71680;                        // [256][384]
  short* p2t  = p1t + 98304;                        // [128][256]
  int*   psum = (int*)(p2t + 32768);                // [128] scan partials
  int*   poff = psum + 128;                         // [128] scan offsets

  const int* rowp = eidx;

  (void)hipMemsetAsync(deg, 0, (size_t)(NN + NN) * 4, stream);   // deg + cursor only
  egcl_prep<<<2048, 256, 0, stream>>>(msg_w1, msg_b1, msg_w2, msg_b2,
                                      tr_w1, tr_b1, tr_w2, tr_b2,
                                      posi_w1, posi_w2,
                                      strf, rowp, w1t, w2t, t1t, t2t, p1t, p2t,
                                      strb, deg, msg_sum);
  egcl_scan_a<<<SCB, 512, 0, stream>>>(deg, psum);
  egcl_scan_b<<<1, 128, 0, stream>>>(psum, poff, base);
  egcl_scan_c<<<SCB, 512, 0, stream>>>(deg, poff, base);
  egcl_scatter<<<(NE + 511) / 512, 512, 0, stream>>>(rowp, base, cursor, eidg);
  egcl_edge<<<NE / 64, 256, 0, stream>>>(eidx, coord, strb, eidg, base,
                                         w1t, w2t, t1t, t2t, tr_w3,
                                         msg_sum, trans_sum);
  egcl_node<<<(NN + 63) / 64, 256, 0, stream>>>(strf, coord, strb, p1t, p2t,
                                                posi_b1, posi_b2,
                                                msg_sum, trans_sum, base, out);
}